// Round 12
// baseline (4995.878 us; speedup 1.0000x reference)
//
#include <hip/hip_runtime.h>
#include <math.h>

#define B_ 16
#define S_ 256
#define T_ 256
#define E_ 1024
#define H_ 512
#define G_ 1536
#define V_ 32000

typedef unsigned short u16;
typedef short short8 __attribute__((ext_vector_type(8)));
typedef short short4v __attribute__((ext_vector_type(4)));
typedef float f32x4 __attribute__((ext_vector_type(4)));

__device__ inline u16 f2bf(float x) {
  union { float f; unsigned u; } a; a.f = x;
  unsigned r = a.u + 0x7fff + ((a.u >> 16) & 1);
  return (u16)(r >> 16);
}
// truncation split: hi = top 16 bits, lo = rne(x - trunc16(x)). |err| <= 2^-17|x|.
__device__ inline void split2(float x, u16& hi, u16& lo) {
  union { float f; unsigned u; } a; a.f = x;
  hi = (u16)(a.u >> 16);
  union { unsigned u; float f; } b; b.u = a.u & 0xffff0000u;
  lo = f2bf(x - b.f);
}

// Coherent (MALL-level) 16B load: bypasses L1+L2, no cache maintenance.
// Caller MUST execute s_waitcnt vmcnt(0) before using the result.
__device__ inline f32x4 load_f4_coh(const float* p) {
  f32x4 v;
  asm volatile("global_load_dwordx4 %0, %1, off sc0 sc1" : "=v"(v) : "v"(p));
  return v;
}

__device__ inline float dot4(f32x4 a, f32x4 b) {
  return a.x * b.x + a.y * b.y + a.z * b.z + a.w * b.w;
}

// ---------------- embedding gathers ----------------
__global__ __launch_bounds__(256) void k_embed_enc(const int* __restrict__ sen,
                                                   const float* __restrict__ emb,
                                                   float* __restrict__ out) {
  long row = blockIdx.x;
  int tid = threadIdx.x;
  long e = sen[row];
  float4 v = *(const float4*)(emb + e * E_ + tid * 4);
  *(float4*)(out + row * E_ + tid * 4) = v;
}

__global__ __launch_bounds__(256) void k_embed_dec(const int* __restrict__ zh,
                                                   const float* __restrict__ emb,
                                                   float* __restrict__ out) {
  long row = blockIdx.x;
  int b = (int)(row >> 8), t = (int)(row & 255);
  int tid = threadIdx.x;
  long e = (t == 0) ? (V_ - 2) : zh[b * T_ + t - 1];
  float4 v = *(const float4*)(emb + e * E_ + tid * 4);
  *(float4*)(out + row * E_ + tid * 4) = v;
}

// ---------------- batched 32x32 tiled transpose ----------------
__global__ __launch_bounds__(256) void k_transpose(const float* __restrict__ in,
                                                   float* __restrict__ out, int R, int C) {
  __shared__ float tile[32][33];
  long z = blockIdx.z;
  const float* inz = in + z * (long)R * C;
  float* outz = out + z * (long)R * C;
  int x = blockIdx.x * 32 + threadIdx.x;
  int y0 = blockIdx.y * 32;
#pragma unroll
  for (int i = threadIdx.y; i < 32; i += 8)
    tile[i][threadIdx.x] = inz[(long)(y0 + i) * C + x];
  __syncthreads();
  int xo = y0 + threadIdx.x;
#pragma unroll
  for (int i = threadIdx.y; i < 32; i += 8) {
    int yo = blockIdx.x * 32 + i;
    outz[(long)yo * R + xo] = tile[threadIdx.x][i];
  }
}

// ---------------- fp32 SGEMM (small attention GEMMs) ----------------
__global__ __launch_bounds__(256) void k_gemm_nt(
    const float* __restrict__ A, int lda, const float* __restrict__ A2, int lda2, int kSplit,
    const float* __restrict__ Bm, int ldb, const float* __restrict__ bias,
    float* __restrict__ C, int ldc, int K, long sA, long sB, long sC) {
  __shared__ float As[8][132];
  __shared__ float Bs[8][132];
  int z = blockIdx.z;
  A += z * sA;
  Bm += z * sB;
  C += z * sC;
  int tid = threadIdx.x;
  int bm = blockIdx.y * 128, bn = blockIdx.x * 128;
  int tx = tid & 15, ty = tid >> 4;
  int lr = tid >> 1, lc = (tid & 1) * 4;
  float acc[8][8] = {};
  for (int k0 = 0; k0 < K; k0 += 8) {
    int ka = k0 + lc;
    const float* ap;
    if (A2 != nullptr && ka >= kSplit)
      ap = A2 + (long)(bm + lr) * lda2 + (ka - kSplit);
    else
      ap = A + (long)(bm + lr) * lda + ka;
    float4 a4 = *(const float4*)ap;
    float4 b4 = *(const float4*)(Bm + (long)(bn + lr) * ldb + k0 + lc);
    As[lc + 0][lr] = a4.x; As[lc + 1][lr] = a4.y; As[lc + 2][lr] = a4.z; As[lc + 3][lr] = a4.w;
    Bs[lc + 0][lr] = b4.x; Bs[lc + 1][lr] = b4.y; Bs[lc + 2][lr] = b4.z; Bs[lc + 3][lr] = b4.w;
    __syncthreads();
#pragma unroll
    for (int kk = 0; kk < 8; kk++) {
      float ar[8], br[8];
      *(float4*)&ar[0] = *(const float4*)&As[kk][ty * 8];
      *(float4*)&ar[4] = *(const float4*)&As[kk][ty * 8 + 4];
      *(float4*)&br[0] = *(const float4*)&Bs[kk][tx * 8];
      *(float4*)&br[4] = *(const float4*)&Bs[kk][tx * 8 + 4];
#pragma unroll
      for (int i = 0; i < 8; i++)
#pragma unroll
        for (int j = 0; j < 8; j++) acc[i][j] += ar[i] * br[j];
    }
    __syncthreads();
  }
  float bv[8];
#pragma unroll
  for (int j = 0; j < 8; j++) bv[j] = bias ? bias[bn + tx * 8 + j] : 0.f;
#pragma unroll
  for (int i = 0; i < 8; i++) {
    float* cp = C + (long)(bm + ty * 8 + i) * ldc + bn + tx * 8;
    float4 o0, o1;
    o0.x = acc[i][0] + bv[0]; o0.y = acc[i][1] + bv[1];
    o0.z = acc[i][2] + bv[2]; o0.w = acc[i][3] + bv[3];
    o1.x = acc[i][4] + bv[4]; o1.y = acc[i][5] + bv[5];
    o1.z = acc[i][6] + bv[6]; o1.w = acc[i][7] + bv[7];
    *(float4*)cp = o0;
    *(float4*)(cp + 4) = o1;
  }
}

// ---------------- split-bf16 MFMA GEMM, split-on-stage (projections + FC fallback) ----
// LDS col stride 34 (68B rows): bank = (17*row) % 32 distinct over 16 rows -> ~2-way.
__global__ __launch_bounds__(256) void k_gemm_mfma_nt(
    const float* __restrict__ A, int lda, const float* __restrict__ A2, int lda2, int kSplit,
    const float* __restrict__ Bm, int ldb, const float* __restrict__ bias,
    float* __restrict__ C, int ldc, int K) {
  __shared__ u16 Ah[128][34];
  __shared__ u16 Al[128][34];
  __shared__ u16 Bh[128][34];
  __shared__ u16 Bl[128][34];
  int tid = threadIdx.x;
  int bm = blockIdx.y * 128, bn = blockIdx.x * 128;
  int wave = tid >> 6, lane = tid & 63;
  int wm = (wave >> 1) * 64, wn = (wave & 1) * 64;
  int srow = tid >> 1, scol = (tid & 1) * 16;
  int fr = lane & 15, fk = (lane >> 4) * 8, fq = lane >> 4;

  f32x4 acc[4][4] = {};

  for (int k0 = 0; k0 < K; k0 += 32) {
    {
      int ka = k0 + scol;
      const float* ap;
      if (A2 != nullptr && ka >= kSplit)
        ap = A2 + (long)(bm + srow) * lda2 + (ka - kSplit);
      else
        ap = A + (long)(bm + srow) * lda + ka;
      float va[16];
      *(float4*)&va[0] = *(const float4*)ap;
      *(float4*)&va[4] = *(const float4*)(ap + 4);
      *(float4*)&va[8] = *(const float4*)(ap + 8);
      *(float4*)&va[12] = *(const float4*)(ap + 12);
      u16 h[16], l[16];
#pragma unroll
      for (int i = 0; i < 16; i++) split2(va[i], h[i], l[i]);
      *(short8*)&Ah[srow][scol] = *(short8*)&h[0];
      *(short8*)&Ah[srow][scol + 8] = *(short8*)&h[8];
      *(short8*)&Al[srow][scol] = *(short8*)&l[0];
      *(short8*)&Al[srow][scol + 8] = *(short8*)&l[8];
    }
    {
      const float* bp = Bm + (long)(bn + srow) * ldb + k0 + scol;
      float vb[16];
      *(float4*)&vb[0] = *(const float4*)bp;
      *(float4*)&vb[4] = *(const float4*)(bp + 4);
      *(float4*)&vb[8] = *(const float4*)(bp + 8);
      *(float4*)&vb[12] = *(const float4*)(bp + 12);
      u16 h[16], l[16];
#pragma unroll
      for (int i = 0; i < 16; i++) split2(vb[i], h[i], l[i]);
      *(short8*)&Bh[srow][scol] = *(short8*)&h[0];
      *(short8*)&Bh[srow][scol + 8] = *(short8*)&h[8];
      *(short8*)&Bl[srow][scol] = *(short8*)&l[0];
      *(short8*)&Bl[srow][scol + 8] = *(short8*)&l[8];
    }
    __syncthreads();
    short8 afh[4], afl[4];
#pragma unroll
    for (int mt = 0; mt < 4; mt++) {
      afh[mt] = *(const short8*)&Ah[wm + mt * 16 + fr][fk];
      afl[mt] = *(const short8*)&Al[wm + mt * 16 + fr][fk];
    }
#pragma unroll
    for (int nt = 0; nt < 4; nt++) {
      short8 bh = *(const short8*)&Bh[wn + nt * 16 + fr][fk];
      short8 bl = *(const short8*)&Bl[wn + nt * 16 + fr][fk];
#pragma unroll
      for (int mt = 0; mt < 4; mt++) {
        acc[mt][nt] = __builtin_amdgcn_mfma_f32_16x16x32_bf16(afh[mt], bh, acc[mt][nt], 0, 0, 0);
        acc[mt][nt] = __builtin_amdgcn_mfma_f32_16x16x32_bf16(afh[mt], bl, acc[mt][nt], 0, 0, 0);
        acc[mt][nt] = __builtin_amdgcn_mfma_f32_16x16x32_bf16(afl[mt], bh, acc[mt][nt], 0, 0, 0);
      }
    }
    __syncthreads();
  }
#pragma unroll
  for (int nt = 0; nt < 4; nt++) {
    int col = bn + wn + nt * 16 + fr;
    float bv = bias ? bias[col] : 0.f;
#pragma unroll
    for (int mt = 0; mt < 4; mt++) {
      int row = bm + wm + mt * 16 + fq * 4;
#pragma unroll
      for (int j = 0; j < 4; j++)
        C[(long)(row + j) * ldc + col] = acc[mt][nt][j] + bv;
    }
  }
}

// ---------------- pre-split kernels: fp32 -> (hi,lo) bf16 pairs ----------------
// flat: src[n], 8 elems/thread.
__global__ __launch_bounds__(256) void k_presplit(const float* __restrict__ src,
                                                  u16* __restrict__ hi,
                                                  u16* __restrict__ lo) {
  long i0 = ((long)blockIdx.x * 256 + threadIdx.x) * 8;
  float v[8];
  *(float4*)&v[0] = *(const float4*)(src + i0);
  *(float4*)&v[4] = *(const float4*)(src + i0 + 4);
  u16 h[8], l[8];
#pragma unroll
  for (int i = 0; i < 8; i++) split2(v[i], h[i], l[i]);
  *(short8*)(hi + i0) = *(short8*)&h[0];
  *(short8*)(lo + i0) = *(short8*)&l[0];
}

// concat rows: A[r][0..511]=a[r], A[r][512..1023]=b[r]; one row per block.
__global__ __launch_bounds__(256) void k_presplit_cat(const float* __restrict__ a,
                                                      const float* __restrict__ b,
                                                      u16* __restrict__ hi,
                                                      u16* __restrict__ lo) {
  long row = blockIdx.x;
  int tid = threadIdx.x;
  const float* src = (tid < 128) ? (a + row * 512 + tid * 4)
                                 : (b + row * 512 + (tid - 128) * 4);
  float4 v = *(const float4*)src;
  u16 h[4], l[4];
  split2(v.x, h[0], l[0]); split2(v.y, h[1], l[1]);
  split2(v.z, h[2], l[2]); split2(v.w, h[3], l[3]);
  *(short4v*)(hi + row * 1024 + tid * 4) = *(short4v*)&h[0];
  *(short4v*)(lo + row * 1024 + tid * 4) = *(short4v*)&l[0];
}

// ---------------- pre-split bf16 MFMA GEMM (FC fast path) ----------------
// A,B given as (hi,lo) u16 arrays, row stride = K. Staging has ZERO conversion
// VALU: 8x 16B loads + 8x ds_write_b128 per thread per K=32 tile.
__global__ __launch_bounds__(256) void k_gemm_bf16p_nt(
    const u16* __restrict__ Ahi, const u16* __restrict__ Alo,
    const u16* __restrict__ Bhi, const u16* __restrict__ Blo,
    const float* __restrict__ bias, float* __restrict__ C, int ldc, int K) {
  __shared__ u16 Ah[128][34];
  __shared__ u16 Al[128][34];
  __shared__ u16 Bh[128][34];
  __shared__ u16 Bl[128][34];
  int tid = threadIdx.x;
  int bm = blockIdx.y * 128, bn = blockIdx.x * 128;
  int wave = tid >> 6, lane = tid & 63;
  int wm = (wave >> 1) * 64, wn = (wave & 1) * 64;
  int srow = tid >> 1, scol = (tid & 1) * 16;
  int fr = lane & 15, fk = (lane >> 4) * 8, fq = lane >> 4;

  f32x4 acc[4][4] = {};
  long aoff = (long)(bm + srow) * K + scol;
  long boff = (long)(bn + srow) * K + scol;

  for (int k0 = 0; k0 < K; k0 += 32) {
    short8 ah0 = *(const short8*)(Ahi + aoff + k0);
    short8 ah1 = *(const short8*)(Ahi + aoff + k0 + 8);
    short8 al0 = *(const short8*)(Alo + aoff + k0);
    short8 al1 = *(const short8*)(Alo + aoff + k0 + 8);
    short8 bh0 = *(const short8*)(Bhi + boff + k0);
    short8 bh1 = *(const short8*)(Bhi + boff + k0 + 8);
    short8 bl0 = *(const short8*)(Blo + boff + k0);
    short8 bl1 = *(const short8*)(Blo + boff + k0 + 8);
    *(short8*)&Ah[srow][scol] = ah0;
    *(short8*)&Ah[srow][scol + 8] = ah1;
    *(short8*)&Al[srow][scol] = al0;
    *(short8*)&Al[srow][scol + 8] = al1;
    *(short8*)&Bh[srow][scol] = bh0;
    *(short8*)&Bh[srow][scol + 8] = bh1;
    *(short8*)&Bl[srow][scol] = bl0;
    *(short8*)&Bl[srow][scol + 8] = bl1;
    __syncthreads();
    short8 afh[4], afl[4];
#pragma unroll
    for (int mt = 0; mt < 4; mt++) {
      afh[mt] = *(const short8*)&Ah[wm + mt * 16 + fr][fk];
      afl[mt] = *(const short8*)&Al[wm + mt * 16 + fr][fk];
    }
#pragma unroll
    for (int nt = 0; nt < 4; nt++) {
      short8 bh = *(const short8*)&Bh[wn + nt * 16 + fr][fk];
      short8 bl = *(const short8*)&Bl[wn + nt * 16 + fr][fk];
#pragma unroll
      for (int mt = 0; mt < 4; mt++) {
        acc[mt][nt] = __builtin_amdgcn_mfma_f32_16x16x32_bf16(afh[mt], bh, acc[mt][nt], 0, 0, 0);
        acc[mt][nt] = __builtin_amdgcn_mfma_f32_16x16x32_bf16(afh[mt], bl, acc[mt][nt], 0, 0, 0);
        acc[mt][nt] = __builtin_amdgcn_mfma_f32_16x16x32_bf16(afl[mt], bh, acc[mt][nt], 0, 0, 0);
      }
    }
    __syncthreads();
  }
#pragma unroll
  for (int nt = 0; nt < 4; nt++) {
    int col = bn + wn + nt * 16 + fr;
    float bv = bias ? bias[col] : 0.f;
#pragma unroll
    for (int mt = 0; mt < 4; mt++) {
      int row = bm + wm + mt * 16 + fq * 4;
#pragma unroll
      for (int j = 0; j < 4; j++)
        C[(long)(row + j) * ldc + col] = acc[mt][nt][j] + bv;
    }
  }
}

// ---------------- batch-partitioned persistent GRU layer (round-10 proven, verbatim) ----
#define WSLOT 32
__global__ __launch_bounds__(256) void k_gru_b(
    const float* __restrict__ xp, float* __restrict__ y,
    const float* __restrict__ Whh, const float* __restrict__ bhh,
    const float* __restrict__ hinit, long hbs, int* __restrict__ ep) {
  __shared__ float hls[536];
  int tid = threadIdx.x;
  int wave = tid >> 6, lane = tid & 63;
  int jsub = lane >> 5, ksl = lane & 31;
  int b = blockIdx.x >> 4, js = blockIdx.x & 15;
  int jbase = js * 32 + wave * 8 + jsub * 4;

  f32x4 w[4][3][4];
  float bb[4][3];
#pragma unroll
  for (int e = 0; e < 4; e++)
#pragma unroll
    for (int g = 0; g < 3; g++) {
      const float* r = Whh + (long)(g * 512 + jbase + e) * 512 + ksl * 16;
#pragma unroll
      for (int q = 0; q < 4; q++) w[e][g][q] = *(const f32x4*)(r + q * 4);
      bb[e][g] = bhh[g * 512 + jbase + e];
    }
  bool gl = (ksl < 4);
  int jme = jbase + ksl;
  const int* epb = ep + (long)(b * 16 + (lane & 15)) * WSLOT;
  int* epMine = ep + (long)(b * 16 + js) * WSLOT;
  float* yb = y + (long)b * (256 * 512);
  const float* xpb = xp + (long)b * (256 * 1536);

  for (int t = 0; t < 256; t++) {
    float xr = 0.f, xz = 0.f, xn = 0.f;
    if (gl) {
      const float* xpt = xpb + (long)t * 1536 + jme;
      xr = xpt[0]; xz = xpt[512]; xn = xpt[1024];
    }
    if (t > 0) {
      if (wave == 0) {
        while (true) {
          int e0;
          asm volatile("global_load_dword %0, %1, off sc0 sc1" : "=v"(e0) : "v"(epb));
          asm volatile("s_waitcnt vmcnt(0)" ::: "memory");
          if (__ballot(e0 >= t) == ~0ull) break;
          __builtin_amdgcn_s_sleep(1);
        }
      }
      __syncthreads();
    }
    if (tid < 128) {
      const float* src = (t == 0) ? (hinit + (long)b * hbs + tid * 4)
                                  : (yb + (long)(t - 1) * 512 + tid * 4);
      f32x4 v = load_f4_coh(src);
      asm volatile("s_waitcnt vmcnt(0)" ::: "memory");
      __builtin_amdgcn_sched_barrier(0);
      *(f32x4*)&hls[(tid & 3) * 132 + (tid >> 2) * 4] = v;
    }
    __syncthreads();
    f32x4 h0 = *(const f32x4*)&hls[ksl * 4];
    f32x4 h1 = *(const f32x4*)&hls[132 + ksl * 4];
    f32x4 h2 = *(const f32x4*)&hls[264 + ksl * 4];
    f32x4 h3 = *(const f32x4*)&hls[396 + ksl * 4];
    float a[4][3];
#pragma unroll
    for (int e = 0; e < 4; e++)
#pragma unroll
      for (int g = 0; g < 3; g++)
        a[e][g] = dot4(h0, w[e][g][0]) + dot4(h1, w[e][g][1]) +
                  dot4(h2, w[e][g][2]) + dot4(h3, w[e][g][3]);
#pragma unroll
    for (int m = 1; m <= 16; m <<= 1)
#pragma unroll
      for (int e = 0; e < 4; e++) {
        a[e][0] += __shfl_xor(a[e][0], m);
        a[e][1] += __shfl_xor(a[e][1], m);
        a[e][2] += __shfl_xor(a[e][2], m);
      }
    if (gl) {
      float hr = 0.f, hz = 0.f, hn = 0.f, Br = 0.f, Bz = 0.f, Bn = 0.f;
#pragma unroll
      for (int e = 0; e < 4; e++)
        if (ksl == e) {
          hr = a[e][0]; hz = a[e][1]; hn = a[e][2];
          Br = bb[e][0]; Bz = bb[e][1]; Bn = bb[e][2];
        }
      float r = 1.f / (1.f + __expf(-(xr + hr + Br)));
      float z = 1.f / (1.f + __expf(-(xz + hz + Bz)));
      float n = tanhf(xn + r * (hn + Bn));
      float hp = hls[((jme >> 2) & 3) * 132 + (jme >> 4) * 4 + (jme & 3)];
      float hv = (1.f - z) * n + z * hp;
      __hip_atomic_store(&yb[(long)t * 512 + jme], hv,
                         __ATOMIC_RELAXED, __HIP_MEMORY_SCOPE_AGENT);
    }
    asm volatile("s_waitcnt vmcnt(0)" ::: "memory");
    __syncthreads();
    if (tid == 0)
      __hip_atomic_store(epMine, t + 1, __ATOMIC_RELAXED, __HIP_MEMORY_SCOPE_AGENT);
  }
}

// ---------------- row softmax over 256 ----------------
__global__ __launch_bounds__(256) void k_softmax(float* __restrict__ p) {
  long row = blockIdx.x;
  int tid = threadIdx.x;
  float* pr = p + row * 256;
  float v = pr[tid];
  float m = v;
#pragma unroll
  for (int off = 32; off >= 1; off >>= 1) m = fmaxf(m, __shfl_xor(m, off));
  __shared__ float wmax[4];
  __shared__ float wsum[4];
  int wv = tid >> 6, ln = tid & 63;
  if (ln == 0) wmax[wv] = m;
  __syncthreads();
  m = fmaxf(fmaxf(wmax[0], wmax[1]), fmaxf(wmax[2], wmax[3]));
  float e = expf(v - m);
  float s = e;
#pragma unroll
  for (int off = 32; off >= 1; off >>= 1) s += __shfl_xor(s, off);
  if (ln == 0) wsum[wv] = s;
  __syncthreads();
  s = wsum[0] + wsum[1] + wsum[2] + wsum[3];
  pr[tid] = e / s;
}

extern "C" void kernel_launch(void* const* d_in, const int* in_sizes, int n_in,
                              void* d_out, int out_size, void* d_ws, size_t ws_size,
                              hipStream_t stream) {
  const int* en_sen = (const int*)d_in[0];
  const int* zh_sen = (const int*)d_in[1];
  const float* en_emb = (const float*)d_in[2];
  const float* zh_emb = (const float*)d_in[3];
  const float* h0 = (const float*)d_in[4];
  const float* Wih_e0 = (const float*)d_in[5];
  const float* Whh_e0 = (const float*)d_in[6];
  const float* bih_e0 = (const float*)d_in[7];
  const float* bhh_e0 = (const float*)d_in[8];
  const float* Wih_e1 = (const float*)d_in[9];
  const float* Whh_e1 = (const float*)d_in[10];
  const float* bih_e1 = (const float*)d_in[11];
  const float* bhh_e1 = (const float*)d_in[12];
  const float* Wih_d0 = (const float*)d_in[13];
  const float* Whh_d0 = (const float*)d_in[14];
  const float* bih_d0 = (const float*)d_in[15];
  const float* bhh_d0 = (const float*)d_in[16];
  const float* Wih_d1 = (const float*)d_in[17];
  const float* Whh_d1 = (const float*)d_in[18];
  const float* bih_d1 = (const float*)d_in[19];
  const float* bhh_d1 = (const float*)d_in[20];
  const float* fcW = (const float*)d_in[21];
  const float* fcb = (const float*)d_in[22];
  float* out = (float*)d_out;

  // ---- FC fast path needs d_ws to hold ALL FC inputs (pre-split hi/lo):
  // fcWhi/lo: 2 * 32768000 u16 = 131 MB; Ahi/lo: 2 * 4194304 u16 = 16.8 MB.
  const size_t needFast = (2ull * 32768000 + 2ull * 4194304) * sizeof(u16);
  bool fastFC = (ws_size >= needFast);

  u16* fcWhi = (u16*)d_ws;                 // [32000][1024]
  u16* fcWlo = fcWhi + 32768000;
  u16* Ahi = (u16*)(fcWlo + 32768000);     // [4096][1024]
  u16* Alo = Ahi + 4194304;

  // d_out scratch (all consumed before final FC; FC fast path reads only d_ws).
  int* flags = (int*)d_out;                // [4][256][32] = 32768 ints
  float* bufE = (float*)d_out + 32768;     // ex / zx  [B*256*1024]
  float* xp = bufE + 4194304;              // [B*256*1536]
  float* bufY = xp + 6291456;              // y_e0 then y_d0
  float* enOut = bufY + 2097152;           // y_e1
  float* scT = enOut + 2097152;            // scores/attn [B,T,S]
  float* enOutT = scT + 1048576;           // [B,512,256]
  float* decOutA = enOutT + 2097152;       // fast path: decOut/ctx in d_out
  float* ctxA = decOutA + 2097152;

  // fallback: FC reads decOut/ctx directly -> they must live in d_ws (R2-R10 proven)
  float* decOut = fastFC ? decOutA : (float*)d_ws;
  float* ctx = fastFC ? ctxA : ((float*)d_ws + 2097152);

  hipMemsetAsync(flags, 0, 32768 * sizeof(int), stream);

  dim3 tb(32, 8);

  // pre-split fcW once (independent of everything else)
  if (fastFC)
    k_presplit<<<16000, 256, 0, stream>>>(fcW, fcWhi, fcWlo);

  // ---------------- encoder ----------------
  k_embed_enc<<<B_ * S_, 256, 0, stream>>>(en_sen, en_emb, bufE);
  k_gemm_mfma_nt<<<dim3(G_ / 128, (B_ * S_) / 128, 1), 256, 0, stream>>>(
      bufE, E_, nullptr, 0, E_, Wih_e0, E_, bih_e0, xp, G_, E_);
  k_gru_b<<<256, 256, 0, stream>>>(xp, bufY, Whh_e0, bhh_e0, h0, (long)H_, flags);
  k_gemm_mfma_nt<<<dim3(G_ / 128, (B_ * S_) / 128, 1), 256, 0, stream>>>(
      bufY, H_, nullptr, 0, H_, Wih_e1, H_, bih_e1, xp, G_, H_);
  k_gru_b<<<256, 256, 0, stream>>>(xp, enOut, Whh_e1, bhh_e1, h0 + B_ * H_, (long)H_,
                                   flags + 8192);

  // ---------------- decoder ----------------
  k_embed_dec<<<B_ * T_, 256, 0, stream>>>(zh_sen, zh_emb, bufE);
  k_gemm_mfma_nt<<<dim3(G_ / 128, (B_ * T_) / 128, 1), 256, 0, stream>>>(
      bufE, E_, nullptr, 0, E_, Wih_d0, E_, bih_d0, xp, G_, E_);
  k_gru_b<<<256, 256, 0, stream>>>(xp, bufY, Whh_d0, bhh_d0, bufY + 255 * H_,
                                   (long)(256 * H_), flags + 16384);
  k_gemm_mfma_nt<<<dim3(G_ / 128, (B_ * T_) / 128, 1), 256, 0, stream>>>(
      bufY, H_, nullptr, 0, H_, Wih_d1, H_, bih_d1, xp, G_, H_);
  k_gru_b<<<256, 256, 0, stream>>>(xp, decOut, Whh_d1, bhh_d1, enOut + 255 * H_,
                                   (long)(256 * H_), flags + 24576);

  // ---------------- attention ----------------
  k_gemm_nt<<<dim3(S_ / 128, T_ / 128, B_), 256, 0, stream>>>(
      decOut, H_, nullptr, 0, H_, enOut, H_, nullptr, scT, S_, H_,
      (long)T_ * H_, (long)S_ * H_, (long)T_ * S_);
  k_softmax<<<B_ * T_, 256, 0, stream>>>(scT);
  k_transpose<<<dim3(16, 8, B_), tb, 0, stream>>>(enOut, enOutT, 256, 512);
  k_gemm_nt<<<dim3(H_ / 128, T_ / 128, B_), 256, 0, stream>>>(
      scT, S_, nullptr, 0, S_, enOutT, S_, nullptr, ctx, H_, S_,
      (long)T_ * S_, (long)H_ * S_, (long)T_ * H_);

  // ---------------- final FC ----------------
  if (fastFC) {
    // pre-split A = [decOut|ctx] into d_ws, then pure-bf16 GEMM (reads only d_ws)
    k_presplit_cat<<<B_ * T_, 256, 0, stream>>>(decOut, ctx, Ahi, Alo);
    k_gemm_bf16p_nt<<<dim3(V_ / 128, (B_ * T_) / 128, 1), 256, 0, stream>>>(
        Ahi, Alo, fcWhi, fcWlo, fcb, out, V_, E_);
  } else {
    k_gemm_mfma_nt<<<dim3(V_ / 128, (B_ * T_) / 128, 1), 256, 0, stream>>>(
        decOut, H_, ctx, H_, H_, fcW, E_, fcb, out, V_, E_);
  }
}

// Round 14
// 4691.127 us; speedup vs baseline: 1.0650x; 1.0650x over previous
//
#include <hip/hip_runtime.h>
#include <math.h>

#define B_ 16
#define S_ 256
#define T_ 256
#define E_ 1024
#define H_ 512
#define G_ 1536
#define V_ 32000

typedef unsigned short u16;
typedef unsigned int u32;
typedef short short8 __attribute__((ext_vector_type(8)));
typedef short short4v __attribute__((ext_vector_type(4)));
typedef float f32x4 __attribute__((ext_vector_type(4)));

__device__ inline u16 f2bf(float x) {
  union { float f; unsigned u; } a; a.f = x;
  unsigned r = a.u + 0x7fff + ((a.u >> 16) & 1);
  return (u16)(r >> 16);
}
// truncation split: hi = top 16 bits, lo = rne(x - trunc16(x)). |err| <= 2^-17|x|.
__device__ inline void split2(float x, u16& hi, u16& lo) {
  union { float f; unsigned u; } a; a.f = x;
  hi = (u16)(a.u >> 16);
  union { unsigned u; float f; } b; b.u = a.u & 0xffff0000u;
  lo = f2bf(x - b.f);
}

// Coherent (MALL-level) 16B load: bypasses L1+L2, no cache maintenance.
// Caller MUST execute s_waitcnt vmcnt(0) before using the result.
__device__ inline f32x4 load_f4_coh(const float* p) {
  f32x4 v;
  asm volatile("global_load_dwordx4 %0, %1, off sc0 sc1" : "=v"(v) : "v"(p));
  return v;
}

__device__ inline float dot4(f32x4 a, f32x4 b) {
  return a.x * b.x + a.y * b.y + a.z * b.z + a.w * b.w;
}

// ---------------- embedding gathers ----------------
__global__ __launch_bounds__(256) void k_embed_enc(const int* __restrict__ sen,
                                                   const float* __restrict__ emb,
                                                   float* __restrict__ out) {
  long row = blockIdx.x;
  int tid = threadIdx.x;
  long e = sen[row];
  float4 v = *(const float4*)(emb + e * E_ + tid * 4);
  *(float4*)(out + row * E_ + tid * 4) = v;
}

__global__ __launch_bounds__(256) void k_embed_dec(const int* __restrict__ zh,
                                                   const float* __restrict__ emb,
                                                   float* __restrict__ out) {
  long row = blockIdx.x;
  int b = (int)(row >> 8), t = (int)(row & 255);
  int tid = threadIdx.x;
  long e = (t == 0) ? (V_ - 2) : zh[b * T_ + t - 1];
  float4 v = *(const float4*)(emb + e * E_ + tid * 4);
  *(float4*)(out + row * E_ + tid * 4) = v;
}

// ---------------- batched 32x32 tiled transpose ----------------
__global__ __launch_bounds__(256) void k_transpose(const float* __restrict__ in,
                                                   float* __restrict__ out, int R, int C) {
  __shared__ float tile[32][33];
  long z = blockIdx.z;
  const float* inz = in + z * (long)R * C;
  float* outz = out + z * (long)R * C;
  int x = blockIdx.x * 32 + threadIdx.x;
  int y0 = blockIdx.y * 32;
#pragma unroll
  for (int i = threadIdx.y; i < 32; i += 8)
    tile[i][threadIdx.x] = inz[(long)(y0 + i) * C + x];
  __syncthreads();
  int xo = y0 + threadIdx.x;
#pragma unroll
  for (int i = threadIdx.y; i < 32; i += 8) {
    int yo = blockIdx.x * 32 + i;
    outz[(long)yo * R + xo] = tile[threadIdx.x][i];
  }
}

// ---------------- fp32 SGEMM (small attention GEMMs) ----------------
__global__ __launch_bounds__(256) void k_gemm_nt(
    const float* __restrict__ A, int lda, const float* __restrict__ A2, int lda2, int kSplit,
    const float* __restrict__ Bm, int ldb, const float* __restrict__ bias,
    float* __restrict__ C, int ldc, int K, long sA, long sB, long sC) {
  __shared__ float As[8][132];
  __shared__ float Bs[8][132];
  int z = blockIdx.z;
  A += z * sA;
  Bm += z * sB;
  C += z * sC;
  int tid = threadIdx.x;
  int bm = blockIdx.y * 128, bn = blockIdx.x * 128;
  int tx = tid & 15, ty = tid >> 4;
  int lr = tid >> 1, lc = (tid & 1) * 4;
  float acc[8][8] = {};
  for (int k0 = 0; k0 < K; k0 += 8) {
    int ka = k0 + lc;
    const float* ap;
    if (A2 != nullptr && ka >= kSplit)
      ap = A2 + (long)(bm + lr) * lda2 + (ka - kSplit);
    else
      ap = A + (long)(bm + lr) * lda + ka;
    float4 a4 = *(const float4*)ap;
    float4 b4 = *(const float4*)(Bm + (long)(bn + lr) * ldb + k0 + lc);
    As[lc + 0][lr] = a4.x; As[lc + 1][lr] = a4.y; As[lc + 2][lr] = a4.z; As[lc + 3][lr] = a4.w;
    Bs[lc + 0][lr] = b4.x; Bs[lc + 1][lr] = b4.y; Bs[lc + 2][lr] = b4.z; Bs[lc + 3][lr] = b4.w;
    __syncthreads();
#pragma unroll
    for (int kk = 0; kk < 8; kk++) {
      float ar[8], br[8];
      *(float4*)&ar[0] = *(const float4*)&As[kk][ty * 8];
      *(float4*)&ar[4] = *(const float4*)&As[kk][ty * 8 + 4];
      *(float4*)&br[0] = *(const float4*)&Bs[kk][tx * 8];
      *(float4*)&br[4] = *(const float4*)&Bs[kk][tx * 8 + 4];
#pragma unroll
      for (int i = 0; i < 8; i++)
#pragma unroll
        for (int j = 0; j < 8; j++) acc[i][j] += ar[i] * br[j];
    }
    __syncthreads();
  }
  float bv[8];
#pragma unroll
  for (int j = 0; j < 8; j++) bv[j] = bias ? bias[bn + tx * 8 + j] : 0.f;
#pragma unroll
  for (int i = 0; i < 8; i++) {
    float* cp = C + (long)(bm + ty * 8 + i) * ldc + bn + tx * 8;
    float4 o0, o1;
    o0.x = acc[i][0] + bv[0]; o0.y = acc[i][1] + bv[1];
    o0.z = acc[i][2] + bv[2]; o0.w = acc[i][3] + bv[3];
    o1.x = acc[i][4] + bv[4]; o1.y = acc[i][5] + bv[5];
    o1.z = acc[i][6] + bv[6]; o1.w = acc[i][7] + bv[7];
    *(float4*)cp = o0;
    *(float4*)(cp + 4) = o1;
  }
}

// ======= fragment-major LDS layout for 128x32 bf16 tiles =======
// unit(row in [0,128), q in [0,4)) of 8 u16 (16B), q = k-group (k = q*8..q*8+7):
//   uid = (row>>6)*256 + ((row>>4)&3)*64 + q*16 + (row&15)
// MFMA read for wave (wm in {0,64}), lane: uid = (wm>>6)*256 + mt*64 + lane
//   -> byte addr = base + lane*16  => perfectly linear per wave, zero read conflicts.
// Stage write (srow=tid>>1, q0=(tid&1)*2): units uid(srow,q0), uid(srow,q0)+16.

// ---------------- split-bf16 MFMA GEMM, split-on-stage (projections + FC fallback) ----
__global__ __launch_bounds__(256) void k_gemm_mfma_nt(
    const float* __restrict__ A, int lda, const float* __restrict__ A2, int lda2, int kSplit,
    const float* __restrict__ Bm, int ldb, const float* __restrict__ bias,
    float* __restrict__ C, int ldc, int K) {
  __shared__ short8 Ah[512], Al[512], Bh[512], Bl[512];
  int tid = threadIdx.x;
  int bm = blockIdx.y * 128, bn = blockIdx.x * 128;
  int wave = tid >> 6, lane = tid & 63;
  int wm = (wave >> 1) * 64, wn = (wave & 1) * 64;
  int srow = tid >> 1, scol = (tid & 1) * 16, q0 = (tid & 1) * 2;
  int fr = lane & 15, fq = lane >> 4;
  int ua = (srow >> 6) * 256 + ((srow >> 4) & 3) * 64 + q0 * 16 + (srow & 15);
  int abase = (wm >> 6) * 256 + lane;
  int bbase = (wn >> 6) * 256 + lane;

  f32x4 acc[4][4] = {};

  for (int k0 = 0; k0 < K; k0 += 32) {
    {
      int ka = k0 + scol;
      const float* ap;
      if (A2 != nullptr && ka >= kSplit)
        ap = A2 + (long)(bm + srow) * lda2 + (ka - kSplit);
      else
        ap = A + (long)(bm + srow) * lda + ka;
      float va[16];
      *(float4*)&va[0] = *(const float4*)ap;
      *(float4*)&va[4] = *(const float4*)(ap + 4);
      *(float4*)&va[8] = *(const float4*)(ap + 8);
      *(float4*)&va[12] = *(const float4*)(ap + 12);
      u16 h[16], l[16];
#pragma unroll
      for (int i = 0; i < 16; i++) split2(va[i], h[i], l[i]);
      Ah[ua] = *(short8*)&h[0];
      Ah[ua + 16] = *(short8*)&h[8];
      Al[ua] = *(short8*)&l[0];
      Al[ua + 16] = *(short8*)&l[8];
    }
    {
      const float* bp = Bm + (long)(bn + srow) * ldb + k0 + scol;
      float vb[16];
      *(float4*)&vb[0] = *(const float4*)bp;
      *(float4*)&vb[4] = *(const float4*)(bp + 4);
      *(float4*)&vb[8] = *(const float4*)(bp + 8);
      *(float4*)&vb[12] = *(const float4*)(bp + 12);
      u16 h[16], l[16];
#pragma unroll
      for (int i = 0; i < 16; i++) split2(vb[i], h[i], l[i]);
      Bh[ua] = *(short8*)&h[0];
      Bh[ua + 16] = *(short8*)&h[8];
      Bl[ua] = *(short8*)&l[0];
      Bl[ua + 16] = *(short8*)&l[8];
    }
    __syncthreads();
    short8 afh[4], afl[4];
#pragma unroll
    for (int mt = 0; mt < 4; mt++) {
      afh[mt] = Ah[abase + mt * 64];
      afl[mt] = Al[abase + mt * 64];
    }
#pragma unroll
    for (int nt = 0; nt < 4; nt++) {
      short8 bh = Bh[bbase + nt * 64];
      short8 bl = Bl[bbase + nt * 64];
#pragma unroll
      for (int mt = 0; mt < 4; mt++) {
        acc[mt][nt] = __builtin_amdgcn_mfma_f32_16x16x32_bf16(afh[mt], bh, acc[mt][nt], 0, 0, 0);
        acc[mt][nt] = __builtin_amdgcn_mfma_f32_16x16x32_bf16(afh[mt], bl, acc[mt][nt], 0, 0, 0);
        acc[mt][nt] = __builtin_amdgcn_mfma_f32_16x16x32_bf16(afl[mt], bh, acc[mt][nt], 0, 0, 0);
      }
    }
    __syncthreads();
  }
  int fq4 = fq * 4;
#pragma unroll
  for (int nt = 0; nt < 4; nt++) {
    int col = bn + wn + nt * 16 + fr;
    float bv = bias ? bias[col] : 0.f;
#pragma unroll
    for (int mt = 0; mt < 4; mt++) {
      int row = bm + wm + mt * 16 + fq4;
#pragma unroll
      for (int j = 0; j < 4; j++)
        C[(long)(row + j) * ldc + col] = acc[mt][nt][j] + bv;
    }
  }
}

// ---------------- pre-split kernels: fp32 -> (hi,lo) bf16 pairs ----------------
__global__ __launch_bounds__(256) void k_presplit(const float* __restrict__ src,
                                                  u16* __restrict__ hi,
                                                  u16* __restrict__ lo) {
  long i0 = ((long)blockIdx.x * 256 + threadIdx.x) * 8;
  float v[8];
  *(float4*)&v[0] = *(const float4*)(src + i0);
  *(float4*)&v[4] = *(const float4*)(src + i0 + 4);
  u16 h[8], l[8];
#pragma unroll
  for (int i = 0; i < 8; i++) split2(v[i], h[i], l[i]);
  *(short8*)(hi + i0) = *(short8*)&h[0];
  *(short8*)(lo + i0) = *(short8*)&l[0];
}

// concat rows: A[r][0..511]=a[r], A[r][512..1023]=b[r]; one row per block.
__global__ __launch_bounds__(256) void k_presplit_cat(const float* __restrict__ a,
                                                      const float* __restrict__ b,
                                                      u16* __restrict__ hi,
                                                      u16* __restrict__ lo) {
  long row = blockIdx.x;
  int tid = threadIdx.x;
  const float* src = (tid < 128) ? (a + row * 512 + tid * 4)
                                 : (b + row * 512 + (tid - 128) * 4);
  float4 v = *(const float4*)src;
  u16 h[4], l[4];
  split2(v.x, h[0], l[0]); split2(v.y, h[1], l[1]);
  split2(v.z, h[2], l[2]); split2(v.w, h[3], l[3]);
  *(short4v*)(hi + row * 1024 + tid * 4) = *(short4v*)&h[0];
  *(short4v*)(lo + row * 1024 + tid * 4) = *(short4v*)&l[0];
}

// ---------------- pre-split bf16 MFMA GEMM (FC fast path), fragment-major LDS ------
__global__ __launch_bounds__(256) void k_gemm_bf16p_nt(
    const u16* __restrict__ Ahi, const u16* __restrict__ Alo,
    const u16* __restrict__ Bhi, const u16* __restrict__ Blo,
    const float* __restrict__ bias, float* __restrict__ C, int ldc, int K) {
  __shared__ short8 Ah[512], Al[512], Bh[512], Bl[512];
  int tid = threadIdx.x;
  int bm = blockIdx.y * 128, bn = blockIdx.x * 128;
  int wave = tid >> 6, lane = tid & 63;
  int wm = (wave >> 1) * 64, wn = (wave & 1) * 64;
  int srow = tid >> 1, scol = (tid & 1) * 16, q0 = (tid & 1) * 2;
  int fr = lane & 15, fq = lane >> 4;
  int ua = (srow >> 6) * 256 + ((srow >> 4) & 3) * 64 + q0 * 16 + (srow & 15);
  int abase = (wm >> 6) * 256 + lane;
  int bbase = (wn >> 6) * 256 + lane;

  f32x4 acc[4][4] = {};
  long aoff = (long)(bm + srow) * K + scol;
  long boff = (long)(bn + srow) * K + scol;

  for (int k0 = 0; k0 < K; k0 += 32) {
    short8 ah0 = *(const short8*)(Ahi + aoff + k0);
    short8 ah1 = *(const short8*)(Ahi + aoff + k0 + 8);
    short8 al0 = *(const short8*)(Alo + aoff + k0);
    short8 al1 = *(const short8*)(Alo + aoff + k0 + 8);
    short8 bh0 = *(const short8*)(Bhi + boff + k0);
    short8 bh1 = *(const short8*)(Bhi + boff + k0 + 8);
    short8 bl0 = *(const short8*)(Blo + boff + k0);
    short8 bl1 = *(const short8*)(Blo + boff + k0 + 8);
    Ah[ua] = ah0; Ah[ua + 16] = ah1;
    Al[ua] = al0; Al[ua + 16] = al1;
    Bh[ua] = bh0; Bh[ua + 16] = bh1;
    Bl[ua] = bl0; Bl[ua + 16] = bl1;
    __syncthreads();
    short8 afh[4], afl[4];
#pragma unroll
    for (int mt = 0; mt < 4; mt++) {
      afh[mt] = Ah[abase + mt * 64];
      afl[mt] = Al[abase + mt * 64];
    }
#pragma unroll
    for (int nt = 0; nt < 4; nt++) {
      short8 bh = Bh[bbase + nt * 64];
      short8 bl = Bl[bbase + nt * 64];
#pragma unroll
      for (int mt = 0; mt < 4; mt++) {
        acc[mt][nt] = __builtin_amdgcn_mfma_f32_16x16x32_bf16(afh[mt], bh, acc[mt][nt], 0, 0, 0);
        acc[mt][nt] = __builtin_amdgcn_mfma_f32_16x16x32_bf16(afh[mt], bl, acc[mt][nt], 0, 0, 0);
        acc[mt][nt] = __builtin_amdgcn_mfma_f32_16x16x32_bf16(afl[mt], bh, acc[mt][nt], 0, 0, 0);
      }
    }
    __syncthreads();
  }
  int fq4 = fq * 4;
#pragma unroll
  for (int nt = 0; nt < 4; nt++) {
    int col = bn + wn + nt * 16 + fr;
    float bv = bias ? bias[col] : 0.f;
#pragma unroll
    for (int mt = 0; mt < 4; mt++) {
      int row = bm + wm + mt * 16 + fq4;
#pragma unroll
      for (int j = 0; j < 4; j++)
        C[(long)(row + j) * ldc + col] = acc[mt][nt][j] + bv;
    }
  }
}

// ---------------- batch-partitioned persistent GRU layer (R10-proven, verbatim) ----
#define WSLOT 32
__global__ __launch_bounds__(256) void k_gru_b(
    const float* __restrict__ xp, float* __restrict__ y,
    const float* __restrict__ Whh, const float* __restrict__ bhh,
    const float* __restrict__ hinit, long hbs, int* __restrict__ ep) {
  __shared__ float hls[536];
  int tid = threadIdx.x;
  int wave = tid >> 6, lane = tid & 63;
  int jsub = lane >> 5, ksl = lane & 31;
  int b = blockIdx.x >> 4, js = blockIdx.x & 15;
  int jbase = js * 32 + wave * 8 + jsub * 4;

  f32x4 w[4][3][4];
  float bb[4][3];
#pragma unroll
  for (int e = 0; e < 4; e++)
#pragma unroll
    for (int g = 0; g < 3; g++) {
      const float* r = Whh + (long)(g * 512 + jbase + e) * 512 + ksl * 16;
#pragma unroll
      for (int q = 0; q < 4; q++) w[e][g][q] = *(const f32x4*)(r + q * 4);
      bb[e][g] = bhh[g * 512 + jbase + e];
    }
  bool gl = (ksl < 4);
  int jme = jbase + ksl;
  const int* epb = ep + (long)(b * 16 + (lane & 15)) * WSLOT;
  int* epMine = ep + (long)(b * 16 + js) * WSLOT;
  float* yb = y + (long)b * (256 * 512);
  const float* xpb = xp + (long)b * (256 * 1536);

  for (int t = 0; t < 256; t++) {
    float xr = 0.f, xz = 0.f, xn = 0.f;
    if (gl) {
      const float* xpt = xpb + (long)t * 1536 + jme;
      xr = xpt[0]; xz = xpt[512]; xn = xpt[1024];
    }
    if (t > 0) {
      if (wave == 0) {
        while (true) {
          int e0;
          asm volatile("global_load_dword %0, %1, off sc0 sc1" : "=v"(e0) : "v"(epb));
          asm volatile("s_waitcnt vmcnt(0)" ::: "memory");
          if (__ballot(e0 >= t) == ~0ull) break;
          __builtin_amdgcn_s_sleep(1);
        }
      }
      __syncthreads();
    }
    if (tid < 128) {
      const float* src = (t == 0) ? (hinit + (long)b * hbs + tid * 4)
                                  : (yb + (long)(t - 1) * 512 + tid * 4);
      f32x4 v = load_f4_coh(src);
      asm volatile("s_waitcnt vmcnt(0)" ::: "memory");
      __builtin_amdgcn_sched_barrier(0);
      *(f32x4*)&hls[(tid & 3) * 132 + (tid >> 2) * 4] = v;
    }
    __syncthreads();
    f32x4 h0 = *(const f32x4*)&hls[ksl * 4];
    f32x4 h1 = *(const f32x4*)&hls[132 + ksl * 4];
    f32x4 h2 = *(const f32x4*)&hls[264 + ksl * 4];
    f32x4 h3 = *(const f32x4*)&hls[396 + ksl * 4];
    float a[4][3];
#pragma unroll
    for (int e = 0; e < 4; e++)
#pragma unroll
      for (int g = 0; g < 3; g++)
        a[e][g] = dot4(h0, w[e][g][0]) + dot4(h1, w[e][g][1]) +
                  dot4(h2, w[e][g][2]) + dot4(h3, w[e][g][3]);
#pragma unroll
    for (int m = 1; m <= 16; m <<= 1)
#pragma unroll
      for (int e = 0; e < 4; e++) {
        a[e][0] += __shfl_xor(a[e][0], m);
        a[e][1] += __shfl_xor(a[e][1], m);
        a[e][2] += __shfl_xor(a[e][2], m);
      }
    if (gl) {
      float hr = 0.f, hz = 0.f, hn = 0.f, Br = 0.f, Bz = 0.f, Bn = 0.f;
#pragma unroll
      for (int e = 0; e < 4; e++)
        if (ksl == e) {
          hr = a[e][0]; hz = a[e][1]; hn = a[e][2];
          Br = bb[e][0]; Bz = bb[e][1]; Bn = bb[e][2];
        }
      float r = 1.f / (1.f + __expf(-(xr + hr + Br)));
      float z = 1.f / (1.f + __expf(-(xz + hz + Bz)));
      float n = tanhf(xn + r * (hn + Bn));
      float hp = hls[((jme >> 2) & 3) * 132 + (jme >> 4) * 4 + (jme & 3)];
      float hv = (1.f - z) * n + z * hp;
      __hip_atomic_store(&yb[(long)t * 512 + jme], hv,
                         __ATOMIC_RELAXED, __HIP_MEMORY_SCOPE_AGENT);
    }
    asm volatile("s_waitcnt vmcnt(0)" ::: "memory");
    __syncthreads();
    if (tid == 0)
      __hip_atomic_store(epMine, t + 1, __ATOMIC_RELAXED, __HIP_MEMORY_SCOPE_AGENT);
  }
}

// ---------------- row softmax over 256 ----------------
__global__ __launch_bounds__(256) void k_softmax(float* __restrict__ p) {
  long row = blockIdx.x;
  int tid = threadIdx.x;
  float* pr = p + row * 256;
  float v = pr[tid];
  float m = v;
#pragma unroll
  for (int off = 32; off >= 1; off >>= 1) m = fmaxf(m, __shfl_xor(m, off));
  __shared__ float wmax[4];
  __shared__ float wsum[4];
  int wv = tid >> 6, ln = tid & 63;
  if (ln == 0) wmax[wv] = m;
  __syncthreads();
  m = fmaxf(fmaxf(wmax[0], wmax[1]), fmaxf(wmax[2], wmax[3]));
  float e = expf(v - m);
  float s = e;
#pragma unroll
  for (int off = 32; off >= 1; off >>= 1) s += __shfl_xor(s, off);
  if (ln == 0) wsum[wv] = s;
  __syncthreads();
  s = wsum[0] + wsum[1] + wsum[2] + wsum[3];
  pr[tid] = e / s;
}

extern "C" void kernel_launch(void* const* d_in, const int* in_sizes, int n_in,
                              void* d_out, int out_size, void* d_ws, size_t ws_size,
                              hipStream_t stream) {
  const int* en_sen = (const int*)d_in[0];
  const int* zh_sen = (const int*)d_in[1];
  const float* en_emb = (const float*)d_in[2];
  const float* zh_emb = (const float*)d_in[3];
  const float* h0 = (const float*)d_in[4];
  const float* Wih_e0 = (const float*)d_in[5];
  const float* Whh_e0 = (const float*)d_in[6];
  const float* bih_e0 = (const float*)d_in[7];
  const float* bhh_e0 = (const float*)d_in[8];
  const float* Wih_e1 = (const float*)d_in[9];
  const float* Whh_e1 = (const float*)d_in[10];
  const float* bih_e1 = (const float*)d_in[11];
  const float* bhh_e1 = (const float*)d_in[12];
  const float* Wih_d0 = (const float*)d_in[13];
  const float* Whh_d0 = (const float*)d_in[14];
  const float* bih_d0 = (const float*)d_in[15];
  const float* bhh_d0 = (const float*)d_in[16];
  const float* Wih_d1 = (const float*)d_in[17];
  const float* Whh_d1 = (const float*)d_in[18];
  const float* bih_d1 = (const float*)d_in[19];
  const float* bhh_d1 = (const float*)d_in[20];
  const float* fcW = (const float*)d_in[21];
  const float* fcb = (const float*)d_in[22];
  float* out = (float*)d_out;

  // FC fast path needs d_ws for pre-split hi/lo FC inputs (so FC never reads d_out).
  const size_t needFast = (2ull * 32768000 + 2ull * 4194304) * sizeof(u16);
  bool fastFC = (ws_size >= needFast);

  u16* fcWhi = (u16*)d_ws;                 // [32000][1024]
  u16* fcWlo = fcWhi + 32768000;
  u16* Ahi = (u16*)(fcWlo + 32768000);     // [4096][1024]
  u16* Alo = Ahi + 4194304;

  // d_out scratch (all consumed before final FC; FC fast path reads only d_ws).
  int* flags = (int*)d_out;                // [4][256][32] = 32768 ints
  float* bufE = (float*)d_out + 32768;     // ex / zx  [B*256*1024]
  float* xp = bufE + 4194304;              // [B*256*1536]
  float* bufY = xp + 6291456;              // y_e0 then y_d0
  float* enOut = bufY + 2097152;           // y_e1
  float* scT = enOut + 2097152;            // scores/attn [B,T,S]
  float* enOutT = scT + 1048576;           // [B,512,256]
  float* decOutA = enOutT + 2097152;       // fast path: decOut/ctx in d_out
  float* ctxA = decOutA + 2097152;

  // fallback: FC reads decOut/ctx directly -> they must live in d_ws
  float* decOut = fastFC ? decOutA : (float*)d_ws;
  float* ctx = fastFC ? ctxA : ((float*)d_ws + 2097152);

  hipMemsetAsync(flags, 0, 32768 * sizeof(int), stream);

  dim3 tb(32, 8);

  // pre-split fcW once (independent of everything else)
  if (fastFC)
    k_presplit<<<16000, 256, 0, stream>>>(fcW, fcWhi, fcWlo);

  // ---------------- encoder ----------------
  k_embed_enc<<<B_ * S_, 256, 0, stream>>>(en_sen, en_emb, bufE);
  k_gemm_mfma_nt<<<dim3(G_ / 128, (B_ * S_) / 128, 1), 256, 0, stream>>>(
      bufE, E_, nullptr, 0, E_, Wih_e0, E_, bih_e0, xp, G_, E_);
  k_gru_b<<<256, 256, 0, stream>>>(xp, bufY, Whh_e0, bhh_e0, h0, (long)H_, flags);
  k_gemm_mfma_nt<<<dim3(G_ / 128, (B_ * S_) / 128, 1), 256, 0, stream>>>(
      bufY, H_, nullptr, 0, H_, Wih_e1, H_, bih_e1, xp, G_, H_);
  k_gru_b<<<256, 256, 0, stream>>>(xp, enOut, Whh_e1, bhh_e1, h0 + B_ * H_, (long)H_,
                                   flags + 8192);

  // ---------------- decoder ----------------
  k_embed_dec<<<B_ * T_, 256, 0, stream>>>(zh_sen, zh_emb, bufE);
  k_gemm_mfma_nt<<<dim3(G_ / 128, (B_ * T_) / 128, 1), 256, 0, stream>>>(
      bufE, E_, nullptr, 0, E_, Wih_d0, E_, bih_d0, xp, G_, E_);
  // init h = y_e0[:,255,:] in bufY; row 255 only read at t=0, overwritten at t=255
  k_gru_b<<<256, 256, 0, stream>>>(xp, bufY, Whh_d0, bhh_d0, bufY + 255 * H_,
                                   (long)(256 * H_), flags + 16384);
  k_gemm_mfma_nt<<<dim3(G_ / 128, (B_ * T_) / 128, 1), 256, 0, stream>>>(
      bufY, H_, nullptr, 0, H_, Wih_d1, H_, bih_d1, xp, G_, H_);
  k_gru_b<<<256, 256, 0, stream>>>(xp, decOut, Whh_d1, bhh_d1, enOut + 255 * H_,
                                   (long)(256 * H_), flags + 24576);

  // ---------------- attention ----------------
  k_gemm_nt<<<dim3(S_ / 128, T_ / 128, B_), 256, 0, stream>>>(
      decOut, H_, nullptr, 0, H_, enOut, H_, nullptr, scT, S_, H_,
      (long)T_ * H_, (long)S_ * H_, (long)T_ * S_);
  k_softmax<<<B_ * T_, 256, 0, stream>>>(scT);
  k_transpose<<<dim3(16, 8, B_), tb, 0, stream>>>(enOut, enOutT, 256, 512);
  k_gemm_nt<<<dim3(H_ / 128, T_ / 128, B_), 256, 0, stream>>>(
      scT, S_, nullptr, 0, S_, enOutT, S_, nullptr, ctx, H_, S_,
      (long)T_ * S_, (long)H_ * S_, (long)T_ * H_);

  // ---------------- final FC ----------------
  if (fastFC) {
    k_presplit_cat<<<B_ * T_, 256, 0, stream>>>(decOut, ctx, Ahi, Alo);
    k_gemm_bf16p_nt<<<dim3(V_ / 128, (B_ * T_) / 128, 1), 256, 0, stream>>>(
        Ahi, Alo, fcWhi, fcWlo, fcb, out, V_, E_);
  } else {
    k_gemm_mfma_nt<<<dim3(V_ / 128, (B_ * T_) / 128, 1), 256, 0, stream>>>(
        decOut, H_, ctx, H_, H_, fcW, E_, fcb, out, V_, E_);
  }
}

// Round 15
// 4593.014 us; speedup vs baseline: 1.0877x; 1.0214x over previous
//
#include <hip/hip_runtime.h>
#include <math.h>

#define B_ 16
#define S_ 256
#define T_ 256
#define E_ 1024
#define H_ 512
#define G_ 1536
#define V_ 32000

typedef unsigned short u16;
typedef unsigned int u32;
typedef short short8 __attribute__((ext_vector_type(8)));
typedef short short4v __attribute__((ext_vector_type(4)));
typedef float f32x4 __attribute__((ext_vector_type(4)));

__device__ inline u16 f2bf(float x) {
  union { float f; unsigned u; } a; a.f = x;
  unsigned r = a.u + 0x7fff + ((a.u >> 16) & 1);
  return (u16)(r >> 16);
}
// truncation split: hi = top 16 bits, lo = rne(x - trunc16(x)). |err| <= 2^-17|x|.
__device__ inline void split2(float x, u16& hi, u16& lo) {
  union { float f; unsigned u; } a; a.f = x;
  hi = (u16)(a.u >> 16);
  union { unsigned u; float f; } b; b.u = a.u & 0xffff0000u;
  lo = f2bf(x - b.f);
}

// Coherent (MALL-level) 16B load: bypasses L1+L2, no cache maintenance.
// Caller MUST execute s_waitcnt vmcnt(0) before using the result.
__device__ inline f32x4 load_f4_coh(const float* p) {
  f32x4 v;
  asm volatile("global_load_dwordx4 %0, %1, off sc0 sc1" : "=v"(v) : "v"(p));
  return v;
}

__device__ inline float dot4(f32x4 a, f32x4 b) {
  return a.x * b.x + a.y * b.y + a.z * b.z + a.w * b.w;
}

// ---------------- embedding gathers ----------------
__global__ __launch_bounds__(256) void k_embed_enc(const int* __restrict__ sen,
                                                   const float* __restrict__ emb,
                                                   float* __restrict__ out) {
  long row = blockIdx.x;
  int tid = threadIdx.x;
  long e = sen[row];
  float4 v = *(const float4*)(emb + e * E_ + tid * 4);
  *(float4*)(out + row * E_ + tid * 4) = v;
}

__global__ __launch_bounds__(256) void k_embed_dec(const int* __restrict__ zh,
                                                   const float* __restrict__ emb,
                                                   float* __restrict__ out) {
  long row = blockIdx.x;
  int b = (int)(row >> 8), t = (int)(row & 255);
  int tid = threadIdx.x;
  long e = (t == 0) ? (V_ - 2) : zh[b * T_ + t - 1];
  float4 v = *(const float4*)(emb + e * E_ + tid * 4);
  *(float4*)(out + row * E_ + tid * 4) = v;
}

// ---------------- batched 32x32 tiled transpose ----------------
__global__ __launch_bounds__(256) void k_transpose(const float* __restrict__ in,
                                                   float* __restrict__ out, int R, int C) {
  __shared__ float tile[32][33];
  long z = blockIdx.z;
  const float* inz = in + z * (long)R * C;
  float* outz = out + z * (long)R * C;
  int x = blockIdx.x * 32 + threadIdx.x;
  int y0 = blockIdx.y * 32;
#pragma unroll
  for (int i = threadIdx.y; i < 32; i += 8)
    tile[i][threadIdx.x] = inz[(long)(y0 + i) * C + x];
  __syncthreads();
  int xo = y0 + threadIdx.x;
#pragma unroll
  for (int i = threadIdx.y; i < 32; i += 8) {
    int yo = blockIdx.x * 32 + i;
    outz[(long)yo * R + xo] = tile[threadIdx.x][i];
  }
}

// ---------------- fp32 SGEMM (small attention GEMMs) ----------------
__global__ __launch_bounds__(256) void k_gemm_nt(
    const float* __restrict__ A, int lda, const float* __restrict__ A2, int lda2, int kSplit,
    const float* __restrict__ Bm, int ldb, const float* __restrict__ bias,
    float* __restrict__ C, int ldc, int K, long sA, long sB, long sC) {
  __shared__ float As[8][132];
  __shared__ float Bs[8][132];
  int z = blockIdx.z;
  A += z * sA;
  Bm += z * sB;
  C += z * sC;
  int tid = threadIdx.x;
  int bm = blockIdx.y * 128, bn = blockIdx.x * 128;
  int tx = tid & 15, ty = tid >> 4;
  int lr = tid >> 1, lc = (tid & 1) * 4;
  float acc[8][8] = {};
  for (int k0 = 0; k0 < K; k0 += 8) {
    int ka = k0 + lc;
    const float* ap;
    if (A2 != nullptr && ka >= kSplit)
      ap = A2 + (long)(bm + lr) * lda2 + (ka - kSplit);
    else
      ap = A + (long)(bm + lr) * lda + ka;
    float4 a4 = *(const float4*)ap;
    float4 b4 = *(const float4*)(Bm + (long)(bn + lr) * ldb + k0 + lc);
    As[lc + 0][lr] = a4.x; As[lc + 1][lr] = a4.y; As[lc + 2][lr] = a4.z; As[lc + 3][lr] = a4.w;
    Bs[lc + 0][lr] = b4.x; Bs[lc + 1][lr] = b4.y; Bs[lc + 2][lr] = b4.z; Bs[lc + 3][lr] = b4.w;
    __syncthreads();
#pragma unroll
    for (int kk = 0; kk < 8; kk++) {
      float ar[8], br[8];
      *(float4*)&ar[0] = *(const float4*)&As[kk][ty * 8];
      *(float4*)&ar[4] = *(const float4*)&As[kk][ty * 8 + 4];
      *(float4*)&br[0] = *(const float4*)&Bs[kk][tx * 8];
      *(float4*)&br[4] = *(const float4*)&Bs[kk][tx * 8 + 4];
#pragma unroll
      for (int i = 0; i < 8; i++)
#pragma unroll
        for (int j = 0; j < 8; j++) acc[i][j] += ar[i] * br[j];
    }
    __syncthreads();
  }
  float bv[8];
#pragma unroll
  for (int j = 0; j < 8; j++) bv[j] = bias ? bias[bn + tx * 8 + j] : 0.f;
#pragma unroll
  for (int i = 0; i < 8; i++) {
    float* cp = C + (long)(bm + ty * 8 + i) * ldc + bn + tx * 8;
    float4 o0, o1;
    o0.x = acc[i][0] + bv[0]; o0.y = acc[i][1] + bv[1];
    o0.z = acc[i][2] + bv[2]; o0.w = acc[i][3] + bv[3];
    o1.x = acc[i][4] + bv[4]; o1.y = acc[i][5] + bv[5];
    o1.z = acc[i][6] + bv[6]; o1.w = acc[i][7] + bv[7];
    *(float4*)cp = o0;
    *(float4*)(cp + 4) = o1;
  }
}

// ======= fragment-major LDS layout (v2, write-conflict-free) for 128x32 bf16 tiles ===
// unit(row in [0,128), q in [0,4)) of 8 u16 (16B), q = k-group:
//   uid = (row>>6)*256 + ((row>>4)&3)*64 + q*16 + ((row&15) ^ (q*2))
// Bijective in (row,q). MFMA read (wave wm, lane=fq*16+fr): uid = rb + mt*64 where
//   rb = (wm>>6)*256 + fq*16 + (fr^(fq*2)) -> each 8-lane group covers 8 consecutive
//   units => zero read conflicts. Stage write (srow=tid>>1, q0=(tid&1)*2): units
//   (srow,q0),(srow,q0+1); uid mod 8 = (srow&7)^(q*2) -> 8 lanes hit 8 distinct
//   4-bank groups => zero write conflicts.

// ---------------- split-bf16 MFMA GEMM, split-on-stage (projections + FC fallback) ----
__global__ __launch_bounds__(256) void k_gemm_mfma_nt(
    const float* __restrict__ A, int lda, const float* __restrict__ A2, int lda2, int kSplit,
    const float* __restrict__ Bm, int ldb, const float* __restrict__ bias,
    float* __restrict__ C, int ldc, int K) {
  __shared__ short8 Ah[512], Al[512], Bh[512], Bl[512];
  int tid = threadIdx.x;
  int bm = blockIdx.y * 128, bn = blockIdx.x * 128;
  int wave = tid >> 6, lane = tid & 63;
  int wm = (wave >> 1) * 64, wn = (wave & 1) * 64;
  int srow = tid >> 1, scol = (tid & 1) * 16, q0 = (tid & 1) * 2;
  int fr = lane & 15, fq = lane >> 4;
  int ubase = (srow >> 6) * 256 + ((srow >> 4) & 3) * 64;
  int ua0 = ubase + q0 * 16 + ((srow & 15) ^ (q0 * 2));
  int ua1 = ubase + (q0 + 1) * 16 + ((srow & 15) ^ (q0 * 2 + 2));
  int abase = (wm >> 6) * 256 + fq * 16 + (fr ^ (fq * 2));
  int bbase = (wn >> 6) * 256 + fq * 16 + (fr ^ (fq * 2));

  f32x4 acc[4][4] = {};

  for (int k0 = 0; k0 < K; k0 += 32) {
    {
      int ka = k0 + scol;
      const float* ap;
      if (A2 != nullptr && ka >= kSplit)
        ap = A2 + (long)(bm + srow) * lda2 + (ka - kSplit);
      else
        ap = A + (long)(bm + srow) * lda + ka;
      float va[16];
      *(float4*)&va[0] = *(const float4*)ap;
      *(float4*)&va[4] = *(const float4*)(ap + 4);
      *(float4*)&va[8] = *(const float4*)(ap + 8);
      *(float4*)&va[12] = *(const float4*)(ap + 12);
      u16 h[16], l[16];
#pragma unroll
      for (int i = 0; i < 16; i++) split2(va[i], h[i], l[i]);
      Ah[ua0] = *(short8*)&h[0];
      Ah[ua1] = *(short8*)&h[8];
      Al[ua0] = *(short8*)&l[0];
      Al[ua1] = *(short8*)&l[8];
    }
    {
      const float* bp = Bm + (long)(bn + srow) * ldb + k0 + scol;
      float vb[16];
      *(float4*)&vb[0] = *(const float4*)bp;
      *(float4*)&vb[4] = *(const float4*)(bp + 4);
      *(float4*)&vb[8] = *(const float4*)(bp + 8);
      *(float4*)&vb[12] = *(const float4*)(bp + 12);
      u16 h[16], l[16];
#pragma unroll
      for (int i = 0; i < 16; i++) split2(vb[i], h[i], l[i]);
      Bh[ua0] = *(short8*)&h[0];
      Bh[ua1] = *(short8*)&h[8];
      Bl[ua0] = *(short8*)&l[0];
      Bl[ua1] = *(short8*)&l[8];
    }
    __syncthreads();
    short8 afh[4], afl[4];
#pragma unroll
    for (int mt = 0; mt < 4; mt++) {
      afh[mt] = Ah[abase + mt * 64];
      afl[mt] = Al[abase + mt * 64];
    }
#pragma unroll
    for (int nt = 0; nt < 4; nt++) {
      short8 bh = Bh[bbase + nt * 64];
      short8 bl = Bl[bbase + nt * 64];
#pragma unroll
      for (int mt = 0; mt < 4; mt++) {
        acc[mt][nt] = __builtin_amdgcn_mfma_f32_16x16x32_bf16(afh[mt], bh, acc[mt][nt], 0, 0, 0);
        acc[mt][nt] = __builtin_amdgcn_mfma_f32_16x16x32_bf16(afh[mt], bl, acc[mt][nt], 0, 0, 0);
        acc[mt][nt] = __builtin_amdgcn_mfma_f32_16x16x32_bf16(afl[mt], bh, acc[mt][nt], 0, 0, 0);
      }
    }
    __syncthreads();
  }
  int fq4 = fq * 4;
#pragma unroll
  for (int nt = 0; nt < 4; nt++) {
    int col = bn + wn + nt * 16 + fr;
    float bv = bias ? bias[col] : 0.f;
#pragma unroll
    for (int mt = 0; mt < 4; mt++) {
      int row = bm + wm + mt * 16 + fq4;
#pragma unroll
      for (int j = 0; j < 4; j++)
        C[(long)(row + j) * ldc + col] = acc[mt][nt][j] + bv;
    }
  }
}

// ---------------- pre-split kernels: fp32 -> (hi,lo) bf16 pairs ----------------
__global__ __launch_bounds__(256) void k_presplit(const float* __restrict__ src,
                                                  u16* __restrict__ hi,
                                                  u16* __restrict__ lo) {
  long i0 = ((long)blockIdx.x * 256 + threadIdx.x) * 8;
  float v[8];
  *(float4*)&v[0] = *(const float4*)(src + i0);
  *(float4*)&v[4] = *(const float4*)(src + i0 + 4);
  u16 h[8], l[8];
#pragma unroll
  for (int i = 0; i < 8; i++) split2(v[i], h[i], l[i]);
  *(short8*)(hi + i0) = *(short8*)&h[0];
  *(short8*)(lo + i0) = *(short8*)&l[0];
}

// concat rows: A[r][0..511]=a[r], A[r][512..1023]=b[r]; one row per block.
__global__ __launch_bounds__(256) void k_presplit_cat(const float* __restrict__ a,
                                                      const float* __restrict__ b,
                                                      u16* __restrict__ hi,
                                                      u16* __restrict__ lo) {
  long row = blockIdx.x;
  int tid = threadIdx.x;
  const float* src = (tid < 128) ? (a + row * 512 + tid * 4)
                                 : (b + row * 512 + (tid - 128) * 4);
  float4 v = *(const float4*)src;
  u16 h[4], l[4];
  split2(v.x, h[0], l[0]); split2(v.y, h[1], l[1]);
  split2(v.z, h[2], l[2]); split2(v.w, h[3], l[3]);
  *(short4v*)(hi + row * 1024 + tid * 4) = *(short4v*)&h[0];
  *(short4v*)(lo + row * 1024 + tid * 4) = *(short4v*)&l[0];
}

// ---------------- pre-split bf16 MFMA GEMM (FC fast path) ----------------
// GRID TRANSPOSED: blockIdx.x = m (32 blocks, fastest), blockIdx.y = n (250).
// Consecutive blocks share one 512KB B tile (L2-hit) and sweep A (16.8MB,
// L3-resident) -> fcW fetched ~once from HBM instead of ~20x.
__global__ __launch_bounds__(256) void k_gemm_bf16p_nt(
    const u16* __restrict__ Ahi, const u16* __restrict__ Alo,
    const u16* __restrict__ Bhi, const u16* __restrict__ Blo,
    const float* __restrict__ bias, float* __restrict__ C, int ldc, int K) {
  __shared__ short8 Ah[512], Al[512], Bh[512], Bl[512];
  int tid = threadIdx.x;
  int bm = blockIdx.x * 128, bn = blockIdx.y * 128;
  int wave = tid >> 6, lane = tid & 63;
  int wm = (wave >> 1) * 64, wn = (wave & 1) * 64;
  int srow = tid >> 1, scol = (tid & 1) * 16, q0 = (tid & 1) * 2;
  int fr = lane & 15, fq = lane >> 4;
  int ubase = (srow >> 6) * 256 + ((srow >> 4) & 3) * 64;
  int ua0 = ubase + q0 * 16 + ((srow & 15) ^ (q0 * 2));
  int ua1 = ubase + (q0 + 1) * 16 + ((srow & 15) ^ (q0 * 2 + 2));
  int abase = (wm >> 6) * 256 + fq * 16 + (fr ^ (fq * 2));
  int bbase = (wn >> 6) * 256 + fq * 16 + (fr ^ (fq * 2));

  f32x4 acc[4][4] = {};
  long aoff = (long)(bm + srow) * K + scol;
  long boff = (long)(bn + srow) * K + scol;

  for (int k0 = 0; k0 < K; k0 += 32) {
    short8 ah0 = *(const short8*)(Ahi + aoff + k0);
    short8 ah1 = *(const short8*)(Ahi + aoff + k0 + 8);
    short8 al0 = *(const short8*)(Alo + aoff + k0);
    short8 al1 = *(const short8*)(Alo + aoff + k0 + 8);
    short8 bh0 = *(const short8*)(Bhi + boff + k0);
    short8 bh1 = *(const short8*)(Bhi + boff + k0 + 8);
    short8 bl0 = *(const short8*)(Blo + boff + k0);
    short8 bl1 = *(const short8*)(Blo + boff + k0 + 8);
    Ah[ua0] = ah0; Ah[ua1] = ah1;
    Al[ua0] = al0; Al[ua1] = al1;
    Bh[ua0] = bh0; Bh[ua1] = bh1;
    Bl[ua0] = bl0; Bl[ua1] = bl1;
    __syncthreads();
    short8 afh[4], afl[4];
#pragma unroll
    for (int mt = 0; mt < 4; mt++) {
      afh[mt] = Ah[abase + mt * 64];
      afl[mt] = Al[abase + mt * 64];
    }
#pragma unroll
    for (int nt = 0; nt < 4; nt++) {
      short8 bh = Bh[bbase + nt * 64];
      short8 bl = Bl[bbase + nt * 64];
#pragma unroll
      for (int mt = 0; mt < 4; mt++) {
        acc[mt][nt] = __builtin_amdgcn_mfma_f32_16x16x32_bf16(afh[mt], bh, acc[mt][nt], 0, 0, 0);
        acc[mt][nt] = __builtin_amdgcn_mfma_f32_16x16x32_bf16(afh[mt], bl, acc[mt][nt], 0, 0, 0);
        acc[mt][nt] = __builtin_amdgcn_mfma_f32_16x16x32_bf16(afl[mt], bh, acc[mt][nt], 0, 0, 0);
      }
    }
    __syncthreads();
  }
  int fq4 = fq * 4;
#pragma unroll
  for (int nt = 0; nt < 4; nt++) {
    int col = bn + wn + nt * 16 + fr;
    float bv = bias ? bias[col] : 0.f;
#pragma unroll
    for (int mt = 0; mt < 4; mt++) {
      int row = bm + wm + mt * 16 + fq4;
#pragma unroll
      for (int j = 0; j < 4; j++)
        C[(long)(row + j) * ldc + col] = acc[mt][nt][j] + bv;
    }
  }
}

// ---------------- batch-partitioned persistent GRU layer (R10-proven, verbatim) ----
#define WSLOT 32
__global__ __launch_bounds__(256) void k_gru_b(
    const float* __restrict__ xp, float* __restrict__ y,
    const float* __restrict__ Whh, const float* __restrict__ bhh,
    const float* __restrict__ hinit, long hbs, int* __restrict__ ep) {
  __shared__ float hls[536];
  int tid = threadIdx.x;
  int wave = tid >> 6, lane = tid & 63;
  int jsub = lane >> 5, ksl = lane & 31;
  int b = blockIdx.x >> 4, js = blockIdx.x & 15;
  int jbase = js * 32 + wave * 8 + jsub * 4;

  f32x4 w[4][3][4];
  float bb[4][3];
#pragma unroll
  for (int e = 0; e < 4; e++)
#pragma unroll
    for (int g = 0; g < 3; g++) {
      const float* r = Whh + (long)(g * 512 + jbase + e) * 512 + ksl * 16;
#pragma unroll
      for (int q = 0; q < 4; q++) w[e][g][q] = *(const f32x4*)(r + q * 4);
      bb[e][g] = bhh[g * 512 + jbase + e];
    }
  bool gl = (ksl < 4);
  int jme = jbase + ksl;
  const int* epb = ep + (long)(b * 16 + (lane & 15)) * WSLOT;
  int* epMine = ep + (long)(b * 16 + js) * WSLOT;
  float* yb = y + (long)b * (256 * 512);
  const float* xpb = xp + (long)b * (256 * 1536);

  for (int t = 0; t < 256; t++) {
    float xr = 0.f, xz = 0.f, xn = 0.f;
    if (gl) {
      const float* xpt = xpb + (long)t * 1536 + jme;
      xr = xpt[0]; xz = xpt[512]; xn = xpt[1024];
    }
    if (t > 0) {
      if (wave == 0) {
        while (true) {
          int e0;
          asm volatile("global_load_dword %0, %1, off sc0 sc1" : "=v"(e0) : "v"(epb));
          asm volatile("s_waitcnt vmcnt(0)" ::: "memory");
          if (__ballot(e0 >= t) == ~0ull) break;
          __builtin_amdgcn_s_sleep(1);
        }
      }
      __syncthreads();
    }
    if (tid < 128) {
      const float* src = (t == 0) ? (hinit + (long)b * hbs + tid * 4)
                                  : (yb + (long)(t - 1) * 512 + tid * 4);
      f32x4 v = load_f4_coh(src);
      asm volatile("s_waitcnt vmcnt(0)" ::: "memory");
      __builtin_amdgcn_sched_barrier(0);
      *(f32x4*)&hls[(tid & 3) * 132 + (tid >> 2) * 4] = v;
    }
    __syncthreads();
    f32x4 h0 = *(const f32x4*)&hls[ksl * 4];
    f32x4 h1 = *(const f32x4*)&hls[132 + ksl * 4];
    f32x4 h2 = *(const f32x4*)&hls[264 + ksl * 4];
    f32x4 h3 = *(const f32x4*)&hls[396 + ksl * 4];
    float a[4][3];
#pragma unroll
    for (int e = 0; e < 4; e++)
#pragma unroll
      for (int g = 0; g < 3; g++)
        a[e][g] = dot4(h0, w[e][g][0]) + dot4(h1, w[e][g][1]) +
                  dot4(h2, w[e][g][2]) + dot4(h3, w[e][g][3]);
#pragma unroll
    for (int m = 1; m <= 16; m <<= 1)
#pragma unroll
      for (int e = 0; e < 4; e++) {
        a[e][0] += __shfl_xor(a[e][0], m);
        a[e][1] += __shfl_xor(a[e][1], m);
        a[e][2] += __shfl_xor(a[e][2], m);
      }
    if (gl) {
      float hr = 0.f, hz = 0.f, hn = 0.f, Br = 0.f, Bz = 0.f, Bn = 0.f;
#pragma unroll
      for (int e = 0; e < 4; e++)
        if (ksl == e) {
          hr = a[e][0]; hz = a[e][1]; hn = a[e][2];
          Br = bb[e][0]; Bz = bb[e][1]; Bn = bb[e][2];
        }
      float r = 1.f / (1.f + __expf(-(xr + hr + Br)));
      float z = 1.f / (1.f + __expf(-(xz + hz + Bz)));
      float n = tanhf(xn + r * (hn + Bn));
      float hp = hls[((jme >> 2) & 3) * 132 + (jme >> 4) * 4 + (jme & 3)];
      float hv = (1.f - z) * n + z * hp;
      __hip_atomic_store(&yb[(long)t * 512 + jme], hv,
                         __ATOMIC_RELAXED, __HIP_MEMORY_SCOPE_AGENT);
    }
    asm volatile("s_waitcnt vmcnt(0)" ::: "memory");
    __syncthreads();
    if (tid == 0)
      __hip_atomic_store(epMine, t + 1, __ATOMIC_RELAXED, __HIP_MEMORY_SCOPE_AGENT);
  }
}

// ---------------- row softmax over 256 ----------------
__global__ __launch_bounds__(256) void k_softmax(float* __restrict__ p) {
  long row = blockIdx.x;
  int tid = threadIdx.x;
  float* pr = p + row * 256;
  float v = pr[tid];
  float m = v;
#pragma unroll
  for (int off = 32; off >= 1; off >>= 1) m = fmaxf(m, __shfl_xor(m, off));
  __shared__ float wmax[4];
  __shared__ float wsum[4];
  int wv = tid >> 6, ln = tid & 63;
  if (ln == 0) wmax[wv] = m;
  __syncthreads();
  m = fmaxf(fmaxf(wmax[0], wmax[1]), fmaxf(wmax[2], wmax[3]));
  float e = expf(v - m);
  float s = e;
#pragma unroll
  for (int off = 32; off >= 1; off >>= 1) s += __shfl_xor(s, off);
  if (ln == 0) wsum[wv] = s;
  __syncthreads();
  s = wsum[0] + wsum[1] + wsum[2] + wsum[3];
  pr[tid] = e / s;
}

extern "C" void kernel_launch(void* const* d_in, const int* in_sizes, int n_in,
                              void* d_out, int out_size, void* d_ws, size_t ws_size,
                              hipStream_t stream) {
  const int* en_sen = (const int*)d_in[0];
  const int* zh_sen = (const int*)d_in[1];
  const float* en_emb = (const float*)d_in[2];
  const float* zh_emb = (const float*)d_in[3];
  const float* h0 = (const float*)d_in[4];
  const float* Wih_e0 = (const float*)d_in[5];
  const float* Whh_e0 = (const float*)d_in[6];
  const float* bih_e0 = (const float*)d_in[7];
  const float* bhh_e0 = (const float*)d_in[8];
  const float* Wih_e1 = (const float*)d_in[9];
  const float* Whh_e1 = (const float*)d_in[10];
  const float* bih_e1 = (const float*)d_in[11];
  const float* bhh_e1 = (const float*)d_in[12];
  const float* Wih_d0 = (const float*)d_in[13];
  const float* Whh_d0 = (const float*)d_in[14];
  const float* bih_d0 = (const float*)d_in[15];
  const float* bhh_d0 = (const float*)d_in[16];
  const float* Wih_d1 = (const float*)d_in[17];
  const float* Whh_d1 = (const float*)d_in[18];
  const float* bih_d1 = (const float*)d_in[19];
  const float* bhh_d1 = (const float*)d_in[20];
  const float* fcW = (const float*)d_in[21];
  const float* fcb = (const float*)d_in[22];
  float* out = (float*)d_out;

  // FC fast path needs d_ws for pre-split hi/lo FC inputs (so FC never reads d_out).
  const size_t needFast = (2ull * 32768000 + 2ull * 4194304) * sizeof(u16);
  bool fastFC = (ws_size >= needFast);

  u16* fcWhi = (u16*)d_ws;                 // [32000][1024]
  u16* fcWlo = fcWhi + 32768000;
  u16* Ahi = (u16*)(fcWlo + 32768000);     // [4096][1024]
  u16* Alo = Ahi + 4194304;

  // d_out scratch (all consumed before final FC; FC fast path reads only d_ws).
  int* flags = (int*)d_out;                // [4][256][32] = 32768 ints
  float* bufE = (float*)d_out + 32768;     // ex / zx  [B*256*1024]
  float* xp = bufE + 4194304;              // [B*256*1536]
  float* bufY = xp + 6291456;              // y_e0 then y_d0
  float* enOut = bufY + 2097152;           // y_e1
  float* scT = enOut + 2097152;            // scores/attn [B,T,S]
  float* enOutT = scT + 1048576;           // [B,512,256]
  float* decOutA = enOutT + 2097152;       // fast path: decOut/ctx in d_out
  float* ctxA = decOutA + 2097152;

  // fallback: FC reads decOut/ctx directly -> they must live in d_ws
  float* decOut = fastFC ? decOutA : (float*)d_ws;
  float* ctx = fastFC ? ctxA : ((float*)d_ws + 2097152);

  hipMemsetAsync(flags, 0, 32768 * sizeof(int), stream);

  dim3 tb(32, 8);

  // pre-split fcW once (independent of everything else)
  if (fastFC)
    k_presplit<<<16000, 256, 0, stream>>>(fcW, fcWhi, fcWlo);

  // ---------------- encoder ----------------
  k_embed_enc<<<B_ * S_, 256, 0, stream>>>(en_sen, en_emb, bufE);
  k_gemm_mfma_nt<<<dim3(G_ / 128, (B_ * S_) / 128, 1), 256, 0, stream>>>(
      bufE, E_, nullptr, 0, E_, Wih_e0, E_, bih_e0, xp, G_, E_);
  k_gru_b<<<256, 256, 0, stream>>>(xp, bufY, Whh_e0, bhh_e0, h0, (long)H_, flags);
  k_gemm_mfma_nt<<<dim3(G_ / 128, (B_ * S_) / 128, 1), 256, 0, stream>>>(
      bufY, H_, nullptr, 0, H_, Wih_e1, H_, bih_e1, xp, G_, H_);
  k_gru_b<<<256, 256, 0, stream>>>(xp, enOut, Whh_e1, bhh_e1, h0 + B_ * H_, (long)H_,
                                   flags + 8192);

  // ---------------- decoder ----------------
  k_embed_dec<<<B_ * T_, 256, 0, stream>>>(zh_sen, zh_emb, bufE);
  k_gemm_mfma_nt<<<dim3(G_ / 128, (B_ * T_) / 128, 1), 256, 0, stream>>>(
      bufE, E_, nullptr, 0, E_, Wih_d0, E_, bih_d0, xp, G_, E_);
  // init h = y_e0[:,255,:] in bufY; row 255 only read at t=0, overwritten at t=255
  k_gru_b<<<256, 256, 0, stream>>>(xp, bufY, Whh_d0, bhh_d0, bufY + 255 * H_,
                                   (long)(256 * H_), flags + 16384);
  k_gemm_mfma_nt<<<dim3(G_ / 128, (B_ * T_) / 128, 1), 256, 0, stream>>>(
      bufY, H_, nullptr, 0, H_, Wih_d1, H_, bih_d1, xp, G_, H_);
  k_gru_b<<<256, 256, 0, stream>>>(xp, decOut, Whh_d1, bhh_d1, enOut + 255 * H_,
                                   (long)(256 * H_), flags + 24576);

  // ---------------- attention ----------------
  k_gemm_nt<<<dim3(S_ / 128, T_ / 128, B_), 256, 0, stream>>>(
      decOut, H_, nullptr, 0, H_, enOut, H_, nullptr, scT, S_, H_,
      (long)T_ * H_, (long)S_ * H_, (long)T_ * S_);
  k_softmax<<<B_ * T_, 256, 0, stream>>>(scT);
  k_transpose<<<dim3(16, 8, B_), tb, 0, stream>>>(enOut, enOutT, 256, 512);
  k_gemm_nt<<<dim3(H_ / 128, T_ / 128, B_), 256, 0, stream>>>(
      scT, S_, nullptr, 0, S_, enOutT, S_, nullptr, ctx, H_, S_,
      (long)T_ * S_, (long)H_ * S_, (long)T_ * H_);

  // ---------------- final FC ----------------
  if (fastFC) {
    k_presplit_cat<<<B_ * T_, 256, 0, stream>>>(decOut, ctx, Ahi, Alo);
    // grid transposed: x = m (32, fastest) -> consecutive blocks share B tile
    k_gemm_bf16p_nt<<<dim3((B_ * T_) / 128, V_ / 128, 1), 256, 0, stream>>>(
        Ahi, Alo, fcWhi, fcWlo, fcb, out, V_, E_);
  } else {
    k_gemm_mfma_nt<<<dim3(V_ / 128, (B_ * T_) / 128, 1), 256, 0, stream>>>(
        decOut, H_, ctx, H_, H_, fcW, E_, fcb, out, V_, E_);
  }
}

// Round 16
// 3997.983 us; speedup vs baseline: 1.2496x; 1.1488x over previous
//
#include <hip/hip_runtime.h>
#include <math.h>

#define B_ 16
#define S_ 256
#define T_ 256
#define E_ 1024
#define H_ 512
#define G_ 1536
#define V_ 32000

typedef unsigned short u16;
typedef unsigned int u32;
typedef short short8 __attribute__((ext_vector_type(8)));
typedef short short4v __attribute__((ext_vector_type(4)));
typedef float f32x4 __attribute__((ext_vector_type(4)));
typedef unsigned int u32x2 __attribute__((ext_vector_type(2)));

__device__ inline u16 f2bf(float x) {
  union { float f; unsigned u; } a; a.f = x;
  unsigned r = a.u + 0x7fff + ((a.u >> 16) & 1);
  return (u16)(r >> 16);
}
// truncation split: hi = top 16 bits, lo = rne(x - trunc16(x)). |err| <= 2^-17|x|.
__device__ inline void split2(float x, u16& hi, u16& lo) {
  union { float f; unsigned u; } a; a.f = x;
  hi = (u16)(a.u >> 16);
  union { unsigned u; float f; } b; b.u = a.u & 0xffff0000u;
  lo = f2bf(x - b.f);
}

// Coherent (MALL-level) 16B load: bypasses L1+L2, no cache maintenance.
// Caller MUST execute s_waitcnt vmcnt(0) before using the result.
__device__ inline f32x4 load_f4_coh(const float* p) {
  f32x4 v;
  asm volatile("global_load_dwordx4 %0, %1, off sc0 sc1" : "=v"(v) : "v"(p));
  return v;
}

__device__ inline float dot4(f32x4 a, f32x4 b) {
  return a.x * b.x + a.y * b.y + a.z * b.z + a.w * b.w;
}

// ---------------- embedding gathers ----------------
__global__ __launch_bounds__(256) void k_embed_enc(const int* __restrict__ sen,
                                                   const float* __restrict__ emb,
                                                   float* __restrict__ out) {
  long row = blockIdx.x;
  int tid = threadIdx.x;
  long e = sen[row];
  float4 v = *(const float4*)(emb + e * E_ + tid * 4);
  *(float4*)(out + row * E_ + tid * 4) = v;
}

__global__ __launch_bounds__(256) void k_embed_dec(const int* __restrict__ zh,
                                                   const float* __restrict__ emb,
                                                   float* __restrict__ out) {
  long row = blockIdx.x;
  int b = (int)(row >> 8), t = (int)(row & 255);
  int tid = threadIdx.x;
  long e = (t == 0) ? (V_ - 2) : zh[b * T_ + t - 1];
  float4 v = *(const float4*)(emb + e * E_ + tid * 4);
  *(float4*)(out + row * E_ + tid * 4) = v;
}

// ---------------- batched 32x32 tiled transpose ----------------
__global__ __launch_bounds__(256) void k_transpose(const float* __restrict__ in,
                                                   float* __restrict__ out, int R, int C) {
  __shared__ float tile[32][33];
  long z = blockIdx.z;
  const float* inz = in + z * (long)R * C;
  float* outz = out + z * (long)R * C;
  int x = blockIdx.x * 32 + threadIdx.x;
  int y0 = blockIdx.y * 32;
#pragma unroll
  for (int i = threadIdx.y; i < 32; i += 8)
    tile[i][threadIdx.x] = inz[(long)(y0 + i) * C + x];
  __syncthreads();
  int xo = y0 + threadIdx.x;
#pragma unroll
  for (int i = threadIdx.y; i < 32; i += 8) {
    int yo = blockIdx.x * 32 + i;
    outz[(long)yo * R + xo] = tile[threadIdx.x][i];
  }
}

// ---------------- fp32 SGEMM (small attention GEMMs) ----------------
__global__ __launch_bounds__(256) void k_gemm_nt(
    const float* __restrict__ A, int lda, const float* __restrict__ A2, int lda2, int kSplit,
    const float* __restrict__ Bm, int ldb, const float* __restrict__ bias,
    float* __restrict__ C, int ldc, int K, long sA, long sB, long sC) {
  __shared__ float As[8][132];
  __shared__ float Bs[8][132];
  int z = blockIdx.z;
  A += z * sA;
  Bm += z * sB;
  C += z * sC;
  int tid = threadIdx.x;
  int bm = blockIdx.y * 128, bn = blockIdx.x * 128;
  int tx = tid & 15, ty = tid >> 4;
  int lr = tid >> 1, lc = (tid & 1) * 4;
  float acc[8][8] = {};
  for (int k0 = 0; k0 < K; k0 += 8) {
    int ka = k0 + lc;
    const float* ap;
    if (A2 != nullptr && ka >= kSplit)
      ap = A2 + (long)(bm + lr) * lda2 + (ka - kSplit);
    else
      ap = A + (long)(bm + lr) * lda + ka;
    float4 a4 = *(const float4*)ap;
    float4 b4 = *(const float4*)(Bm + (long)(bn + lr) * ldb + k0 + lc);
    As[lc + 0][lr] = a4.x; As[lc + 1][lr] = a4.y; As[lc + 2][lr] = a4.z; As[lc + 3][lr] = a4.w;
    Bs[lc + 0][lr] = b4.x; Bs[lc + 1][lr] = b4.y; Bs[lc + 2][lr] = b4.z; Bs[lc + 3][lr] = b4.w;
    __syncthreads();
#pragma unroll
    for (int kk = 0; kk < 8; kk++) {
      float ar[8], br[8];
      *(float4*)&ar[0] = *(const float4*)&As[kk][ty * 8];
      *(float4*)&ar[4] = *(const float4*)&As[kk][ty * 8 + 4];
      *(float4*)&br[0] = *(const float4*)&Bs[kk][tx * 8];
      *(float4*)&br[4] = *(const float4*)&Bs[kk][tx * 8 + 4];
#pragma unroll
      for (int i = 0; i < 8; i++)
#pragma unroll
        for (int j = 0; j < 8; j++) acc[i][j] += ar[i] * br[j];
    }
    __syncthreads();
  }
  float bv[8];
#pragma unroll
  for (int j = 0; j < 8; j++) bv[j] = bias ? bias[bn + tx * 8 + j] : 0.f;
#pragma unroll
  for (int i = 0; i < 8; i++) {
    float* cp = C + (long)(bm + ty * 8 + i) * ldc + bn + tx * 8;
    float4 o0, o1;
    o0.x = acc[i][0] + bv[0]; o0.y = acc[i][1] + bv[1];
    o0.z = acc[i][2] + bv[2]; o0.w = acc[i][3] + bv[3];
    o1.x = acc[i][4] + bv[4]; o1.y = acc[i][5] + bv[5];
    o1.z = acc[i][6] + bv[6]; o1.w = acc[i][7] + bv[7];
    *(float4*)cp = o0;
    *(float4*)(cp + 4) = o1;
  }
}

// ======= fragment-major LDS layout (v2, write-conflict-free) for 128x32 bf16 tiles ===
// unit(row,q) = (row>>6)*256 + ((row>>4)&3)*64 + q*16 + ((row&15) ^ (q*2)); bijective.
// Reads: each 8-lane group covers 8 consecutive units (zero conflicts).
// Writes: uid mod 8 distinct across paired lanes (zero conflicts). R14-validated.

// ---------------- split-bf16 MFMA GEMM, split-on-stage (projections + FC fallback) ----
__global__ __launch_bounds__(256) void k_gemm_mfma_nt(
    const float* __restrict__ A, int lda, const float* __restrict__ A2, int lda2, int kSplit,
    const float* __restrict__ Bm, int ldb, const float* __restrict__ bias,
    float* __restrict__ C, int ldc, int K) {
  __shared__ short8 Ah[512], Al[512], Bh[512], Bl[512];
  int tid = threadIdx.x;
  int bm = blockIdx.y * 128, bn = blockIdx.x * 128;
  int wave = tid >> 6, lane = tid & 63;
  int wm = (wave >> 1) * 64, wn = (wave & 1) * 64;
  int srow = tid >> 1, scol = (tid & 1) * 16, q0 = (tid & 1) * 2;
  int fr = lane & 15, fq = lane >> 4;
  int ubase = (srow >> 6) * 256 + ((srow >> 4) & 3) * 64;
  int ua0 = ubase + q0 * 16 + ((srow & 15) ^ (q0 * 2));
  int ua1 = ubase + (q0 + 1) * 16 + ((srow & 15) ^ (q0 * 2 + 2));
  int abase = (wm >> 6) * 256 + fq * 16 + (fr ^ (fq * 2));
  int bbase = (wn >> 6) * 256 + fq * 16 + (fr ^ (fq * 2));

  f32x4 acc[4][4] = {};

  for (int k0 = 0; k0 < K; k0 += 32) {
    {
      int ka = k0 + scol;
      const float* ap;
      if (A2 != nullptr && ka >= kSplit)
        ap = A2 + (long)(bm + srow) * lda2 + (ka - kSplit);
      else
        ap = A + (long)(bm + srow) * lda + ka;
      float va[16];
      *(float4*)&va[0] = *(const float4*)ap;
      *(float4*)&va[4] = *(const float4*)(ap + 4);
      *(float4*)&va[8] = *(const float4*)(ap + 8);
      *(float4*)&va[12] = *(const float4*)(ap + 12);
      u16 h[16], l[16];
#pragma unroll
      for (int i = 0; i < 16; i++) split2(va[i], h[i], l[i]);
      Ah[ua0] = *(short8*)&h[0];
      Ah[ua1] = *(short8*)&h[8];
      Al[ua0] = *(short8*)&l[0];
      Al[ua1] = *(short8*)&l[8];
    }
    {
      const float* bp = Bm + (long)(bn + srow) * ldb + k0 + scol;
      float vb[16];
      *(float4*)&vb[0] = *(const float4*)bp;
      *(float4*)&vb[4] = *(const float4*)(bp + 4);
      *(float4*)&vb[8] = *(const float4*)(bp + 8);
      *(float4*)&vb[12] = *(const float4*)(bp + 12);
      u16 h[16], l[16];
#pragma unroll
      for (int i = 0; i < 16; i++) split2(vb[i], h[i], l[i]);
      Bh[ua0] = *(short8*)&h[0];
      Bh[ua1] = *(short8*)&h[8];
      Bl[ua0] = *(short8*)&l[0];
      Bl[ua1] = *(short8*)&l[8];
    }
    __syncthreads();
    short8 afh[4], afl[4];
#pragma unroll
    for (int mt = 0; mt < 4; mt++) {
      afh[mt] = Ah[abase + mt * 64];
      afl[mt] = Al[abase + mt * 64];
    }
#pragma unroll
    for (int nt = 0; nt < 4; nt++) {
      short8 bh = Bh[bbase + nt * 64];
      short8 bl = Bl[bbase + nt * 64];
#pragma unroll
      for (int mt = 0; mt < 4; mt++) {
        acc[mt][nt] = __builtin_amdgcn_mfma_f32_16x16x32_bf16(afh[mt], bh, acc[mt][nt], 0, 0, 0);
        acc[mt][nt] = __builtin_amdgcn_mfma_f32_16x16x32_bf16(afh[mt], bl, acc[mt][nt], 0, 0, 0);
        acc[mt][nt] = __builtin_amdgcn_mfma_f32_16x16x32_bf16(afl[mt], bh, acc[mt][nt], 0, 0, 0);
      }
    }
    __syncthreads();
  }
  int fq4 = fq * 4;
#pragma unroll
  for (int nt = 0; nt < 4; nt++) {
    int col = bn + wn + nt * 16 + fr;
    float bv = bias ? bias[col] : 0.f;
#pragma unroll
    for (int mt = 0; mt < 4; mt++) {
      int row = bm + wm + mt * 16 + fq4;
#pragma unroll
      for (int j = 0; j < 4; j++)
        C[(long)(row + j) * ldc + col] = acc[mt][nt][j] + bv;
    }
  }
}

// ---------------- pre-split kernels: fp32 -> (hi,lo) bf16 pairs ----------------
__global__ __launch_bounds__(256) void k_presplit(const float* __restrict__ src,
                                                  u16* __restrict__ hi,
                                                  u16* __restrict__ lo) {
  long i0 = ((long)blockIdx.x * 256 + threadIdx.x) * 8;
  float v[8];
  *(float4*)&v[0] = *(const float4*)(src + i0);
  *(float4*)&v[4] = *(const float4*)(src + i0 + 4);
  u16 h[8], l[8];
#pragma unroll
  for (int i = 0; i < 8; i++) split2(v[i], h[i], l[i]);
  *(short8*)(hi + i0) = *(short8*)&h[0];
  *(short8*)(lo + i0) = *(short8*)&l[0];
}

// concat rows: A[r][0..511]=a[r], A[r][512..1023]=b[r]; one row per block.
__global__ __launch_bounds__(256) void k_presplit_cat(const float* __restrict__ a,
                                                      const float* __restrict__ b,
                                                      u16* __restrict__ hi,
                                                      u16* __restrict__ lo) {
  long row = blockIdx.x;
  int tid = threadIdx.x;
  const float* src = (tid < 128) ? (a + row * 512 + tid * 4)
                                 : (b + row * 512 + (tid - 128) * 4);
  float4 v = *(const float4*)src;
  u16 h[4], l[4];
  split2(v.x, h[0], l[0]); split2(v.y, h[1], l[1]);
  split2(v.z, h[2], l[2]); split2(v.w, h[3], l[3]);
  *(short4v*)(hi + row * 1024 + tid * 4) = *(short4v*)&h[0];
  *(short4v*)(lo + row * 1024 + tid * 4) = *(short4v*)&l[0];
}

// ---------------- pre-split bf16 MFMA GEMM (FC fast path) ----------------
// Grid transposed (x=m fastest): consecutive blocks share one B tile (L2-hit).
__global__ __launch_bounds__(256) void k_gemm_bf16p_nt(
    const u16* __restrict__ Ahi, const u16* __restrict__ Alo,
    const u16* __restrict__ Bhi, const u16* __restrict__ Blo,
    const float* __restrict__ bias, float* __restrict__ C, int ldc, int K) {
  __shared__ short8 Ah[512], Al[512], Bh[512], Bl[512];
  int tid = threadIdx.x;
  int bm = blockIdx.x * 128, bn = blockIdx.y * 128;
  int wave = tid >> 6, lane = tid & 63;
  int wm = (wave >> 1) * 64, wn = (wave & 1) * 64;
  int srow = tid >> 1, scol = (tid & 1) * 16, q0 = (tid & 1) * 2;
  int fr = lane & 15, fq = lane >> 4;
  int ubase = (srow >> 6) * 256 + ((srow >> 4) & 3) * 64;
  int ua0 = ubase + q0 * 16 + ((srow & 15) ^ (q0 * 2));
  int ua1 = ubase + (q0 + 1) * 16 + ((srow & 15) ^ (q0 * 2 + 2));
  int abase = (wm >> 6) * 256 + fq * 16 + (fr ^ (fq * 2));
  int bbase = (wn >> 6) * 256 + fq * 16 + (fr ^ (fq * 2));

  f32x4 acc[4][4] = {};
  long aoff = (long)(bm + srow) * K + scol;
  long boff = (long)(bn + srow) * K + scol;

  for (int k0 = 0; k0 < K; k0 += 32) {
    short8 ah0 = *(const short8*)(Ahi + aoff + k0);
    short8 ah1 = *(const short8*)(Ahi + aoff + k0 + 8);
    short8 al0 = *(const short8*)(Alo + aoff + k0);
    short8 al1 = *(const short8*)(Alo + aoff + k0 + 8);
    short8 bh0 = *(const short8*)(Bhi + boff + k0);
    short8 bh1 = *(const short8*)(Bhi + boff + k0 + 8);
    short8 bl0 = *(const short8*)(Blo + boff + k0);
    short8 bl1 = *(const short8*)(Blo + boff + k0 + 8);
    Ah[ua0] = ah0; Ah[ua1] = ah1;
    Al[ua0] = al0; Al[ua1] = al1;
    Bh[ua0] = bh0; Bh[ua1] = bh1;
    Bl[ua0] = bl0; Bl[ua1] = bl1;
    __syncthreads();
    short8 afh[4], afl[4];
#pragma unroll
    for (int mt = 0; mt < 4; mt++) {
      afh[mt] = Ah[abase + mt * 64];
      afl[mt] = Al[abase + mt * 64];
    }
#pragma unroll
    for (int nt = 0; nt < 4; nt++) {
      short8 bh = Bh[bbase + nt * 64];
      short8 bl = Bl[bbase + nt * 64];
#pragma unroll
      for (int mt = 0; mt < 4; mt++) {
        acc[mt][nt] = __builtin_amdgcn_mfma_f32_16x16x32_bf16(afh[mt], bh, acc[mt][nt], 0, 0, 0);
        acc[mt][nt] = __builtin_amdgcn_mfma_f32_16x16x32_bf16(afh[mt], bl, acc[mt][nt], 0, 0, 0);
        acc[mt][nt] = __builtin_amdgcn_mfma_f32_16x16x32_bf16(afl[mt], bh, acc[mt][nt], 0, 0, 0);
      }
    }
    __syncthreads();
  }
  int fq4 = fq * 4;
#pragma unroll
  for (int nt = 0; nt < 4; nt++) {
    int col = bn + wn + nt * 16 + fr;
    float bv = bias ? bias[col] : 0.f;
#pragma unroll
    for (int mt = 0; mt < 4; mt++) {
      int row = bm + wm + mt * 16 + fq4;
#pragma unroll
      for (int j = 0; j < 4; j++)
        C[(long)(row + j) * ldc + col] = acc[mt][nt][j] + bv;
    }
  }
}

// ---------------- batch-partitioned persistent GRU (LL tagged packets, v2) ----------
// R10-proven partition/matvec. Sync: producer gate lane stores (h_bits, t+1) as ONE
// 8B global_store_dwordx2 sc0 sc1 (single-copy atomic at MALL; RCCL-LL granularity).
// Consumer spin-loads TWO separate 8B dwordx2 packets (match store granularity
// exactly -- no cross-packet atomicity assumption) until both tags == t. Data rides
// with the flag -> ONE MALL round-trip per step (vs 3 in the epoch scheme).
// pkt layout per layer: [16 b][256 t][512 j][2 u32]  (4,194,304 u32; R13's bug was
// sizing this as 262,144 -- packets aliased xp/bufE).
// Determinism: pkt region zeroed at call start; tags in [1,256] only ever written
// by this call's producers; zero/poison never matches.
__global__ __launch_bounds__(256) void k_gru_b(
    const float* __restrict__ xp, float* __restrict__ y,
    const float* __restrict__ Whh, const float* __restrict__ bhh,
    const float* __restrict__ hinit, long hbs, u32* __restrict__ pkt) {
  __shared__ float hls[536];
  int tid = threadIdx.x;
  int wave = tid >> 6, lane = tid & 63;
  int jsub = lane >> 5, ksl = lane & 31;
  int b = blockIdx.x >> 4, js = blockIdx.x & 15;
  int jbase = js * 32 + wave * 8 + jsub * 4;

  f32x4 w[4][3][4];
  float bb[4][3];
#pragma unroll
  for (int e = 0; e < 4; e++)
#pragma unroll
    for (int g = 0; g < 3; g++) {
      const float* r = Whh + (long)(g * 512 + jbase + e) * 512 + ksl * 16;
#pragma unroll
      for (int q = 0; q < 4; q++) w[e][g][q] = *(const f32x4*)(r + q * 4);
      bb[e][g] = bhh[g * 512 + jbase + e];
    }
  bool gl = (ksl < 4);
  int jme = jbase + ksl;
  float* yb = y + (long)b * (256 * 512);
  const float* xpb = xp + (long)b * (256 * 1536);
  u32* pkb = pkt + (long)b * (256 * 512 * 2);
  // this thread's two consumer j's: tid and tid+256
  int cj0 = tid, cj1 = tid + 256;
  int cp0 = ((cj0 >> 2) & 3) * 132 + (cj0 >> 4) * 4 + (cj0 & 3);
  int cp1 = ((cj1 >> 2) & 3) * 132 + (cj1 >> 4) * 4 + (cj1 & 3);

  for (int t = 0; t < 256; t++) {
    // ---- xp prefetch for gate lanes (independent of recurrence) ----
    float xr = 0.f, xz = 0.f, xn = 0.f;
    if (gl) {
      const float* xpt = xpb + (long)t * 1536 + jme;
      xr = xpt[0]; xz = xpt[512]; xn = xpt[1024];
    }
    // ---- stage h(t-1): LL packets (t>0) or hinit (t==0) ----
    if (t > 0) {
      const u32* pp0 = pkb + ((long)(t - 1) * 512 + cj0) * 2;
      const u32* pp1 = pkb + ((long)(t - 1) * 512 + cj1) * 2;
      u32x2 p0, p1;
      while (true) {
        asm volatile("global_load_dwordx2 %0, %1, off sc0 sc1" : "=v"(p0) : "v"(pp0));
        asm volatile("global_load_dwordx2 %0, %1, off sc0 sc1" : "=v"(p1) : "v"(pp1));
        asm volatile("s_waitcnt vmcnt(0)" ::: "memory");
        if (p0.y == (u32)t && p1.y == (u32)t) break;
        __builtin_amdgcn_s_sleep(1);
      }
      union { u32 u; float f; } c0, c1;
      c0.u = p0.x; c1.u = p1.x;
      hls[cp0] = c0.f;
      hls[cp1] = c1.f;
    } else if (tid < 128) {
      const float* src = hinit + (long)b * hbs + tid * 4;
      f32x4 v = load_f4_coh(src);
      asm volatile("s_waitcnt vmcnt(0)" ::: "memory");
      __builtin_amdgcn_sched_barrier(0);
      *(f32x4*)&hls[(tid & 3) * 132 + (tid >> 2) * 4] = v;
    }
    __syncthreads();
    // ---- matvec: 4 j x 3 gates over own 16 k, weights in regs ----
    f32x4 h0 = *(const f32x4*)&hls[ksl * 4];
    f32x4 h1 = *(const f32x4*)&hls[132 + ksl * 4];
    f32x4 h2 = *(const f32x4*)&hls[264 + ksl * 4];
    f32x4 h3 = *(const f32x4*)&hls[396 + ksl * 4];
    float a[4][3];
#pragma unroll
    for (int e = 0; e < 4; e++)
#pragma unroll
      for (int g = 0; g < 3; g++)
        a[e][g] = dot4(h0, w[e][g][0]) + dot4(h1, w[e][g][1]) +
                  dot4(h2, w[e][g][2]) + dot4(h3, w[e][g][3]);
#pragma unroll
    for (int m = 1; m <= 16; m <<= 1)
#pragma unroll
      for (int e = 0; e < 4; e++) {
        a[e][0] += __shfl_xor(a[e][0], m);
        a[e][1] += __shfl_xor(a[e][1], m);
        a[e][2] += __shfl_xor(a[e][2], m);
      }
    // ---- gates + LL publish (fire-and-forget) ----
    if (gl) {
      float hr = 0.f, hz = 0.f, hn = 0.f, Br = 0.f, Bz = 0.f, Bn = 0.f;
#pragma unroll
      for (int e = 0; e < 4; e++)
        if (ksl == e) {
          hr = a[e][0]; hz = a[e][1]; hn = a[e][2];
          Br = bb[e][0]; Bz = bb[e][1]; Bn = bb[e][2];
        }
      float r = 1.f / (1.f + __expf(-(xr + hr + Br)));
      float z = 1.f / (1.f + __expf(-(xz + hz + Bz)));
      float n = tanhf(xn + r * (hn + Bn));
      float hp = hls[((jme >> 2) & 3) * 132 + (jme >> 4) * 4 + (jme & 3)];
      float hv = (1.f - z) * n + z * hp;
      union { float f; u32 u; } hb; hb.f = hv;
      u32x2 pkv;
      pkv.x = hb.u; pkv.y = (u32)(t + 1);
      asm volatile("global_store_dwordx2 %0, %1, off sc0 sc1"
                   ::"v"(pkb + ((long)t * 512 + jme) * 2), "v"(pkv) : "memory");
      yb[(long)t * 512 + jme] = hv;  // plain store for post-kernel consumers
    }
    __syncthreads();  // all hls readers done before next iteration's stage writes
  }
}

// ---------------- row softmax over 256 ----------------
__global__ __launch_bounds__(256) void k_softmax(float* __restrict__ p) {
  long row = blockIdx.x;
  int tid = threadIdx.x;
  float* pr = p + row * 256;
  float v = pr[tid];
  float m = v;
#pragma unroll
  for (int off = 32; off >= 1; off >>= 1) m = fmaxf(m, __shfl_xor(m, off));
  __shared__ float wmax[4];
  __shared__ float wsum[4];
  int wv = tid >> 6, ln = tid & 63;
  if (ln == 0) wmax[wv] = m;
  __syncthreads();
  m = fmaxf(fmaxf(wmax[0], wmax[1]), fmaxf(wmax[2], wmax[3]));
  float e = expf(v - m);
  float s = e;
#pragma unroll
  for (int off = 32; off >= 1; off >>= 1) s += __shfl_xor(s, off);
  if (ln == 0) wsum[wv] = s;
  __syncthreads();
  s = wsum[0] + wsum[1] + wsum[2] + wsum[3];
  pr[tid] = e / s;
}

extern "C" void kernel_launch(void* const* d_in, const int* in_sizes, int n_in,
                              void* d_out, int out_size, void* d_ws, size_t ws_size,
                              hipStream_t stream) {
  const int* en_sen = (const int*)d_in[0];
  const int* zh_sen = (const int*)d_in[1];
  const float* en_emb = (const float*)d_in[2];
  const float* zh_emb = (const float*)d_in[3];
  const float* h0 = (const float*)d_in[4];
  const float* Wih_e0 = (const float*)d_in[5];
  const float* Whh_e0 = (const float*)d_in[6];
  const float* bih_e0 = (const float*)d_in[7];
  const float* bhh_e0 = (const float*)d_in[8];
  const float* Wih_e1 = (const float*)d_in[9];
  const float* Whh_e1 = (const float*)d_in[10];
  const float* bih_e1 = (const float*)d_in[11];
  const float* bhh_e1 = (const float*)d_in[12];
  const float* Wih_d0 = (const float*)d_in[13];
  const float* Whh_d0 = (const float*)d_in[14];
  const float* bih_d0 = (const float*)d_in[15];
  const float* bhh_d0 = (const float*)d_in[16];
  const float* Wih_d1 = (const float*)d_in[17];
  const float* Whh_d1 = (const float*)d_in[18];
  const float* bih_d1 = (const float*)d_in[19];
  const float* bhh_d1 = (const float*)d_in[20];
  const float* fcW = (const float*)d_in[21];
  const float* fcb = (const float*)d_in[22];
  float* out = (float*)d_out;

  // FC fast path needs d_ws for pre-split hi/lo FC inputs (so FC never reads d_out).
  const size_t needFast = (2ull * 32768000 + 2ull * 4194304) * sizeof(u16);
  bool fastFC = (ws_size >= needFast);

  u16* fcWhi = (u16*)d_ws;                 // [32000][1024]
  u16* fcWlo = fcWhi + 32768000;
  u16* Ahi = (u16*)(fcWlo + 32768000);     // [4096][1024]
  u16* Alo = Ahi + 4194304;

  // d_out scratch (all consumed before final FC; FC fast path reads only d_ws):
  // pkts: 4 layers x [16 b][256 t][512 j][2 u32] = 4 x 4,194,304 u32 = 64 MB.
  const long PKL = 4194304;
  u32* pkts = (u32*)d_out;                   // 16,777,216 u32
  float* bufE = (float*)d_out + 16777216;    // ex / zx  [B*256*1024]
  float* xp = bufE + 4194304;                // [B*256*1536]
  float* bufY = xp + 6291456;                // y_e0 then y_d0
  float* enOut = bufY + 2097152;             // y_e1
  float* scT = enOut + 2097152;              // scores/attn [B,T,S]
  float* enOutT = scT + 1048576;             // [B,512,256]
  float* decOutA = enOutT + 2097152;         // fast path: decOut/ctx in d_out
  float* ctxA = decOutA + 2097152;           // (total ~38.8M floats < 131M)

  float* decOut = fastFC ? decOutA : (float*)d_ws;
  float* ctx = fastFC ? ctxA : ((float*)d_ws + 2097152);

  // zero all packet tags each call: full determinism, no stale-tag reasoning
  hipMemsetAsync(pkts, 0, 4 * PKL * sizeof(u32), stream);

  dim3 tb(32, 8);

  // pre-split fcW once (independent of everything else)
  if (fastFC)
    k_presplit<<<16000, 256, 0, stream>>>(fcW, fcWhi, fcWlo);

  // ---------------- encoder ----------------
  k_embed_enc<<<B_ * S_, 256, 0, stream>>>(en_sen, en_emb, bufE);
  k_gemm_mfma_nt<<<dim3(G_ / 128, (B_ * S_) / 128, 1), 256, 0, stream>>>(
      bufE, E_, nullptr, 0, E_, Wih_e0, E_, bih_e0, xp, G_, E_);
  k_gru_b<<<256, 256, 0, stream>>>(xp, bufY, Whh_e0, bhh_e0, h0, (long)H_, pkts);
  k_gemm_mfma_nt<<<dim3(G_ / 128, (B_ * S_) / 128, 1), 256, 0, stream>>>(
      bufY, H_, nullptr, 0, H_, Wih_e1, H_, bih_e1, xp, G_, H_);
  k_gru_b<<<256, 256, 0, stream>>>(xp, enOut, Whh_e1, bhh_e1, h0 + B_ * H_, (long)H_,
                                   pkts + PKL);

  // ---------------- decoder ----------------
  k_embed_dec<<<B_ * T_, 256, 0, stream>>>(zh_sen, zh_emb, bufE);
  k_gemm_mfma_nt<<<dim3(G_ / 128, (B_ * T_) / 128, 1), 256, 0, stream>>>(
      bufE, E_, nullptr, 0, E_, Wih_d0, E_, bih_d0, xp, G_, E_);
  // init h = y_e0[:,255,:] in bufY; row 255 only read at t=0, overwritten at t=255
  k_gru_b<<<256, 256, 0, stream>>>(xp, bufY, Whh_d0, bhh_d0, bufY + 255 * H_,
                                   (long)(256 * H_), pkts + 2 * PKL);
  k_gemm_mfma_nt<<<dim3(G_ / 128, (B_ * T_) / 128, 1), 256, 0, stream>>>(
      bufY, H_, nullptr, 0, H_, Wih_d1, H_, bih_d1, xp, G_, H_);
  k_gru_b<<<256, 256, 0, stream>>>(xp, decOut, Whh_d1, bhh_d1, enOut + 255 * H_,
                                   (long)(256 * H_), pkts + 3 * PKL);

  // ---------------- attention ----------------
  k_gemm_nt<<<dim3(S_ / 128, T_ / 128, B_), 256, 0, stream>>>(
      decOut, H_, nullptr, 0, H_, enOut, H_, nullptr, scT, S_, H_,
      (long)T_ * H_, (long)S_ * H_, (long)T_ * S_);
  k_softmax<<<B_ * T_, 256, 0, stream>>>(scT);
  k_transpose<<<dim3(16, 8, B_), tb, 0, stream>>>(enOut, enOutT, 256, 512);
  k_gemm_nt<<<dim3(H_ / 128, T_ / 128, B_), 256, 0, stream>>>(
      scT, S_, nullptr, 0, S_, enOutT, S_, nullptr, ctx, H_, S_,
      (long)T_ * S_, (long)H_ * S_, (long)T_ * H_);

  // ---------------- final FC ----------------
  if (fastFC) {
    k_presplit_cat<<<B_ * T_, 256, 0, stream>>>(decOut, ctx, Ahi, Alo);
    k_gemm_bf16p_nt<<<dim3((B_ * T_) / 128, V_ / 128, 1), 256, 0, stream>>>(
        Ahi, Alo, fcWhi, fcWlo, fcb, out, V_, E_);
  } else {
    k_gemm_mfma_nt<<<dim3(V_ / 128, (B_ * T_) / 128, 1), 256, 0, stream>>>(
        decOut, H_, ctx, H_, H_, fcW, E_, fcb, out, V_, E_);
  }
}